// Round 9
// baseline (395.303 us; speedup 1.0000x reference)
//
#include <hip/hip_runtime.h>

#define NA 100000
#define NB 100000
#define ND 50000
#define HDIM 128
#define DOUT 16
// concatenated dst-node space: rel0 d:[0,ND) rel1 d:[ND,2ND) rel2 a:[2ND,2ND+NA) rel3 b:[2ND+NA,...)
#define NODE_TOT (2*ND + NA + NB)
#define BSH 9
#define BKN 512
#define NBUCKET ((NODE_TOT + BKN - 1) >> BSH)   // 586
#define EPB 4096                                 // edges per block, bucket passes

typedef __attribute__((ext_vector_type(8))) short short8v;   // 8 bf16 (4 VGPRs)
typedef __attribute__((ext_vector_type(4))) float f32x4;

__device__ __forceinline__ unsigned short f2bf(float f) {
    unsigned u = __float_as_uint(f);
    return (unsigned short)((u + 0x7fffu + ((u >> 16) & 1u)) >> 16);
}

struct EdgeT { int node; int src; };
__device__ __forceinline__ EdgeT edge_at(int g,
    const int* __restrict__ s0, const int* __restrict__ d0,
    const int* __restrict__ s1, const int* __restrict__ d1,
    const int* __restrict__ s2, const int* __restrict__ d2,
    const int* __restrict__ s3, const int* __restrict__ d3,
    int E0, int E1, int E2) {
    EdgeT e;
    if (g < E0)             { e.node = d0[g];                    e.src = s0[g]; }
    else if (g < E0+E1)     { e.node = ND + d1[g-E0];            e.src = s1[g-E0]; }
    else if (g < E0+E1+E2)  { e.node = 2*ND + d2[g-E0-E1];       e.src = s2[g-E0-E1]; }
    else                    { e.node = 2*ND+NA + d3[g-E0-E1-E2]; e.src = s3[g-E0-E1-E2]; }
    return e;
}

// ---------------- weights (f32, for the 128->16 path) ----------------
__global__ __launch_bounds__(256) void k_weights(const float* __restrict__ basis,
                                                 const float* __restrict__ coef,
                                                 float* __restrict__ W0, float* __restrict__ W1,
                                                 int r0, int r1, int n) {
    int i = blockIdx.x * 256 + threadIdx.x;
    if (i >= n) return;
    float b0 = basis[i], b1 = basis[n + i];
    W0[i] = coef[r0*2+0]*b0 + coef[r0*2+1]*b1;
    W1[i] = coef[r1*2+0]*b0 + coef[r1*2+1]*b1;
}

// bf16 TRANSPOSED weights for MFMA B-operand: WT[n][k] = W[k][n], 128x128
__global__ __launch_bounds__(256) void k_weights_bfT(const float* __restrict__ basis,
                                                     const float* __restrict__ coef,
                                                     unsigned short* __restrict__ WT0,
                                                     unsigned short* __restrict__ WT1,
                                                     int r0, int r1) {
    int i = blockIdx.x * 256 + threadIdx.x;   // i = k*128 + j
    if (i >= HDIM*HDIM) return;
    int k = i >> 7, j = i & 127;
    float b0 = basis[i], b1 = basis[HDIM*HDIM + i];
    WT0[(size_t)j*HDIM + k] = f2bf(coef[r0*2+0]*b0 + coef[r0*2+1]*b1);
    WT1[(size_t)j*HDIM + k] = f2bf(coef[r1*2+0]*b0 + coef[r1*2+1]*b1);
}

// ---------------- fp32 -> bf16 conversion (8 elems/thread) ----------------
__global__ __launch_bounds__(256) void k_cvt_bf16(const float* __restrict__ in,
                                                  unsigned int* __restrict__ out, int n8) {
    int i = blockIdx.x * 256 + threadIdx.x;
    if (i >= n8) return;
    const float4 a = *(const float4*)(in + (size_t)i*8);
    const float4 b = *(const float4*)(in + (size_t)i*8 + 4);
    uint4 p;
    p.x = (unsigned)f2bf(a.x) | ((unsigned)f2bf(a.y) << 16);
    p.y = (unsigned)f2bf(a.z) | ((unsigned)f2bf(a.w) << 16);
    p.z = (unsigned)f2bf(b.x) | ((unsigned)f2bf(b.y) << 16);
    p.w = (unsigned)f2bf(b.z) | ((unsigned)f2bf(b.w) << 16);
    *(uint4*)(out + (size_t)i*4) = p;
}

// ---------------- bucketed CSR build ----------------
__global__ __launch_bounds__(256) void k_bhist(const int* __restrict__ s0, const int* __restrict__ d0,
                                               const int* __restrict__ s1, const int* __restrict__ d1,
                                               const int* __restrict__ s2, const int* __restrict__ d2,
                                               const int* __restrict__ s3, const int* __restrict__ d3,
                                               int E0, int E1, int E2, int Etot,
                                               int* __restrict__ bcount) {
    __shared__ int h[NBUCKET];
    for (int i = threadIdx.x; i < NBUCKET; i += 256) h[i] = 0;
    __syncthreads();
    int g0 = blockIdx.x * EPB + threadIdx.x;
    #pragma unroll
    for (int i = 0; i < EPB/256; ++i) {
        int g = g0 + i*256;
        if (g < Etot) {
            EdgeT e = edge_at(g, s0,d0,s1,d1,s2,d2,s3,d3, E0,E1,E2);
            atomicAdd(&h[e.node >> BSH], 1);
        }
    }
    __syncthreads();
    for (int i = threadIdx.x; i < NBUCKET; i += 256)
        if (h[i]) atomicAdd(&bcount[i], h[i]);
}

__global__ __launch_bounds__(1024) void k_bscan(const int* __restrict__ bcount,
                                                int* __restrict__ bofs,
                                                int* __restrict__ gcur) {
    __shared__ int sh[1024];
    int t = threadIdx.x;
    sh[t] = (t < NBUCKET) ? bcount[t] : 0;
    __syncthreads();
    for (int off = 1; off < 1024; off <<= 1) {
        int v = (t >= off) ? sh[t - off] : 0;
        __syncthreads();
        sh[t] += v;
        __syncthreads();
    }
    if (t < NBUCKET) {
        bofs[t + 1] = sh[t];
        gcur[t] = sh[t] - bcount[t];
        if (t == 0) bofs[0] = 0;
    }
}

__global__ __launch_bounds__(256) void k_bscatter(const int* __restrict__ s0, const int* __restrict__ d0,
                                                  const int* __restrict__ s1, const int* __restrict__ d1,
                                                  const int* __restrict__ s2, const int* __restrict__ d2,
                                                  const int* __restrict__ s3, const int* __restrict__ d3,
                                                  int E0, int E1, int E2, int Etot,
                                                  int* __restrict__ gcur,
                                                  uint2* __restrict__ pairs) {
    __shared__ int hist[NBUCKET];
    __shared__ int base[NBUCKET];
    for (int i = threadIdx.x; i < NBUCKET; i += 256) hist[i] = 0;
    __syncthreads();
    int g0 = blockIdx.x * EPB + threadIdx.x;
    int nd[EPB/256], sr[EPB/256], rk[EPB/256];
    #pragma unroll
    for (int i = 0; i < EPB/256; ++i) {
        int g = g0 + i*256;
        if (g < Etot) {
            EdgeT e = edge_at(g, s0,d0,s1,d1,s2,d2,s3,d3, E0,E1,E2);
            nd[i] = e.node; sr[i] = e.src;
            rk[i] = atomicAdd(&hist[e.node >> BSH], 1);
        } else nd[i] = -1;
    }
    __syncthreads();
    for (int i = threadIdx.x; i < NBUCKET; i += 256)
        if (hist[i]) base[i] = atomicAdd(&gcur[i], hist[i]);
    __syncthreads();
    #pragma unroll
    for (int i = 0; i < EPB/256; ++i) {
        if (nd[i] >= 0) {
            uint2 p; p.x = (unsigned)nd[i]; p.y = (unsigned)sr[i];
            pairs[base[nd[i] >> BSH] + rk[i]] = p;
        }
    }
}

__global__ __launch_bounds__(256) void k_bdeg(const uint2* __restrict__ pairs,
                                              const int* __restrict__ bofs,
                                              int* __restrict__ deg) {
    __shared__ int ld[BKN];
    int b = blockIdx.x;
    for (int i = threadIdx.x; i < BKN; i += 256) ld[i] = 0;
    __syncthreads();
    int j0 = bofs[b], j1 = bofs[b + 1];
    int nbase = b << BSH;
    for (int j = j0 + threadIdx.x; j < j1; j += 256)
        atomicAdd(&ld[pairs[j].x - nbase], 1);
    __syncthreads();
    for (int i = threadIdx.x; i < BKN && nbase + i < NODE_TOT; i += 256)
        deg[nbase + i] = ld[i];
}

__global__ __launch_bounds__(256) void k_bfill(const uint2* __restrict__ pairs,
                                               const int* __restrict__ bofs,
                                               const int* __restrict__ offs,
                                               int* __restrict__ csr) {
    __shared__ int cur[BKN];
    int b = blockIdx.x;
    int nbase = b << BSH;
    for (int i = threadIdx.x; i < BKN && nbase + i < NODE_TOT; i += 256)
        cur[i] = offs[nbase + i];
    __syncthreads();
    int j0 = bofs[b], j1 = bofs[b + 1];
    for (int j = j0 + threadIdx.x; j < j1; j += 256) {
        uint2 e = pairs[j];
        int p = atomicAdd(&cur[e.x - nbase], 1);
        csr[p] = (int)e.y;
    }
}

// ---------------- global scans over NODE_TOT (deg -> offs) ----------------
__global__ __launch_bounds__(1024) void k_scan1(const int* __restrict__ deg,
                                                int* __restrict__ offs,
                                                int* __restrict__ bsum, int N) {
    __shared__ int sh[1024];
    int i = blockIdx.x * 1024 + threadIdx.x;
    int v = (i < N) ? deg[i] : 0;
    sh[threadIdx.x] = v;
    __syncthreads();
    for (int off = 1; off < 1024; off <<= 1) {
        int t = (threadIdx.x >= off) ? sh[threadIdx.x - off] : 0;
        __syncthreads();
        sh[threadIdx.x] += t;
        __syncthreads();
    }
    if (i < N) offs[i + 1] = sh[threadIdx.x];
    if (threadIdx.x == 1023) bsum[blockIdx.x] = sh[1023];
    if (i == 0) offs[0] = 0;
}

__global__ __launch_bounds__(1024) void k_scan2(int* __restrict__ bsum, int nb) {
    __shared__ int sh[1024];
    int t = threadIdx.x;
    sh[t] = (t < nb) ? bsum[t] : 0;
    __syncthreads();
    for (int off = 1; off < 1024; off <<= 1) {
        int v = (t >= off) ? sh[t - off] : 0;
        __syncthreads();
        sh[t] += v;
        __syncthreads();
    }
    if (t < nb) bsum[t] = sh[t];
}

__global__ __launch_bounds__(1024) void k_scan3(int* __restrict__ offs,
                                                const int* __restrict__ bsum, int N) {
    int i = blockIdx.x * 1024 + threadIdx.x;
    if (blockIdx.x > 0 && i < N) offs[i + 1] += bsum[blockIdx.x - 1];
}

// ---------------- gather (bf16 table -> bf16 out, CSR, mean) ----------------
__global__ __launch_bounds__(256) void k_gather128_bf(const unsigned int* __restrict__ tbl,
                                                      const int* __restrict__ offs,
                                                      const int* __restrict__ csr,
                                                      unsigned int* __restrict__ outbf, int nrows) {
    int w = threadIdx.x >> 6;
    int lane = threadIdx.x & 63;
    int row = blockIdx.x * 4 + w;
    if (row >= nrows) return;
    int s0 = offs[row], s1 = offs[row + 1];
    float ax = 0.f, ay = 0.f;
    int j = s0;
    for (; j + 1 < s1; j += 2) {
        unsigned u1 = tbl[(size_t)csr[j]*64 + lane];
        unsigned u2 = tbl[(size_t)csr[j+1]*64 + lane];
        ax += __uint_as_float(u1 << 16) + __uint_as_float(u2 << 16);
        ay += __uint_as_float(u1 & 0xffff0000u) + __uint_as_float(u2 & 0xffff0000u);
    }
    if (j < s1) {
        unsigned u1 = tbl[(size_t)csr[j]*64 + lane];
        ax += __uint_as_float(u1 << 16);
        ay += __uint_as_float(u1 & 0xffff0000u);
    }
    float sc = 1.0f / fmaxf((float)(s1 - s0), 1.0f);
    outbf[(size_t)row*64 + lane] =
        (unsigned)f2bf(ax*sc) | ((unsigned)f2bf(ay*sc) << 16);
}

// ---------------- MFMA GEMM: out_bf16[n,128] = [relu]( A0@W0 (+A1@W1) + bias ) ----------------
// A bf16 [n][128]; WT bf16 [128][128] TRANSPOSED (WT[n][k]); 64 rows x 128 cols per block.
// 4 waves; wave w owns cols [w*32, w*32+32). Fragments per verified m89 layout.
__global__ __launch_bounds__(256) void k_mfma_gemm(const unsigned short* __restrict__ A0,
                                                   const unsigned short* __restrict__ A1,
                                                   const unsigned short* __restrict__ WT0,
                                                   const unsigned short* __restrict__ WT1,
                                                   const float* __restrict__ bias, int relu,
                                                   unsigned short* __restrict__ outbf, int nrows) {
    const int l = threadIdx.x & 63;
    const int w = threadIdx.x >> 6;
    const int row0 = blockIdx.x * 64;
    const int colw = w * 32;
    const int kl = (l >> 4) * 8;
    const int rl = l & 15;

    f32x4 acc[4][2];
    #pragma unroll
    for (int r = 0; r < 4; ++r) { acc[r][0] = (f32x4)0.f; acc[r][1] = (f32x4)0.f; }
    const short8v az = {0,0,0,0,0,0,0,0};

    #pragma unroll
    for (int s = 0; s < 4; ++s) {
        const int k0 = s * 32;
        short8v b0 = *(const short8v*)(WT0 + (size_t)(colw + rl)*HDIM + k0 + kl);
        short8v b1 = *(const short8v*)(WT0 + (size_t)(colw + 16 + rl)*HDIM + k0 + kl);
        short8v a[4];
        #pragma unroll
        for (int r = 0; r < 4; ++r) {
            int row = row0 + r*16 + rl;
            a[r] = (row < nrows) ? *(const short8v*)(A0 + (size_t)row*HDIM + k0 + kl) : az;
        }
        #pragma unroll
        for (int r = 0; r < 4; ++r) {
            acc[r][0] = __builtin_amdgcn_mfma_f32_16x16x32_bf16(a[r], b0, acc[r][0], 0, 0, 0);
            acc[r][1] = __builtin_amdgcn_mfma_f32_16x16x32_bf16(a[r], b1, acc[r][1], 0, 0, 0);
        }
    }
    if (A1) {
        #pragma unroll
        for (int s = 0; s < 4; ++s) {
            const int k0 = s * 32;
            short8v b0 = *(const short8v*)(WT1 + (size_t)(colw + rl)*HDIM + k0 + kl);
            short8v b1 = *(const short8v*)(WT1 + (size_t)(colw + 16 + rl)*HDIM + k0 + kl);
            short8v a[4];
            #pragma unroll
            for (int r = 0; r < 4; ++r) {
                int row = row0 + r*16 + rl;
                a[r] = (row < nrows) ? *(const short8v*)(A1 + (size_t)row*HDIM + k0 + kl) : az;
            }
            #pragma unroll
            for (int r = 0; r < 4; ++r) {
                acc[r][0] = __builtin_amdgcn_mfma_f32_16x16x32_bf16(a[r], b0, acc[r][0], 0, 0, 0);
                acc[r][1] = __builtin_amdgcn_mfma_f32_16x16x32_bf16(a[r], b1, acc[r][1], 0, 0, 0);
            }
        }
    }
    // epilogue: D col = colw + c*16 + (l&15); row = row0 + r*16 + (l>>4)*4 + j
    const float bc0 = bias ? bias[colw + rl] : 0.f;
    const float bc1 = bias ? bias[colw + 16 + rl] : 0.f;
    #pragma unroll
    for (int r = 0; r < 4; ++r) {
        #pragma unroll
        for (int j = 0; j < 4; ++j) {
            int row = row0 + r*16 + (l >> 4)*4 + j;
            if (row < nrows) {
                float v0 = acc[r][0][j] + bc0;
                float v1 = acc[r][1][j] + bc1;
                if (relu) { v0 = fmaxf(v0, 0.f); v1 = fmaxf(v1, 0.f); }
                outbf[(size_t)row*HDIM + colw + rl]      = f2bf(v0);
                outbf[(size_t)row*HDIM + colw + 16 + rl] = f2bf(v1);
            }
        }
    }
}

// ---------------- fused layer-1 gather + bias + relu + 128->16 transform ----------------
__global__ __launch_bounds__(256) void k_gather_trans16(const unsigned int* __restrict__ tbl,
                                                        const int* __restrict__ offs,
                                                        const int* __restrict__ csr,
                                                        const float* __restrict__ bias,
                                                        const float* __restrict__ W,
                                                        float* __restrict__ out16, int nrows) {
    __shared__ float Wl[HDIM * DOUT];
    __shared__ float vbuf[16 * 132];
    const int t = threadIdx.x;
    *(float4*)(Wl + t*8)     = *(const float4*)(W + t*8);
    *(float4*)(Wl + t*8 + 4) = *(const float4*)(W + t*8 + 4);
    __syncthreads();
    const int w = t >> 6, lane = t & 63;
    const float b0 = bias[2*lane], b1 = bias[2*lane + 1];
    const int rbase = blockIdx.x * 16 + w * 4;
    #pragma unroll
    for (int r = 0; r < 4; ++r) {
        int row = rbase + r;
        if (row < nrows) {
            int s0 = offs[row], s1 = offs[row + 1];
            float ax = 0.f, ay = 0.f;
            int j = s0;
            for (; j + 1 < s1; j += 2) {
                unsigned u1 = tbl[(size_t)csr[j]*64 + lane];
                unsigned u2 = tbl[(size_t)csr[j+1]*64 + lane];
                ax += __uint_as_float(u1 << 16) + __uint_as_float(u2 << 16);
                ay += __uint_as_float(u1 & 0xffff0000u) + __uint_as_float(u2 & 0xffff0000u);
            }
            if (j < s1) {
                unsigned u1 = tbl[(size_t)csr[j]*64 + lane];
                ax += __uint_as_float(u1 << 16);
                ay += __uint_as_float(u1 & 0xffff0000u);
            }
            float sc = 1.0f / fmaxf((float)(s1 - s0), 1.0f);
            float v0 = fmaxf(ax*sc + b0, 0.f);
            float v1 = fmaxf(ay*sc + b1, 0.f);
            *(float2*)(vbuf + (w*4 + r)*132 + 2*lane) = make_float2(v0, v1);
        }
    }
    __syncthreads();
    const int lr = lane >> 4, jj = lane & 15;
    int row = rbase + lr;
    if (row < nrows) {
        const float* vr = vbuf + (w*4 + lr)*132;
        float acc = 0.f;
        #pragma unroll 8
        for (int c = 0; c < HDIM; ++c)
            acc += vr[c] * Wl[c*DOUT + jj];
        out16[(size_t)row*DOUT + jj] = acc;
    }
}

// final: out[d] = mean-gather(t0 via rel0) + mean-gather(t1 via rel1) + bias
__global__ __launch_bounds__(256) void k_gather16_combine(const float* __restrict__ t0,
                                                          const float* __restrict__ t1,
                                                          const int* __restrict__ offs0,
                                                          const int* __restrict__ offs1,
                                                          const int* __restrict__ csr,
                                                          const float* __restrict__ bias,
                                                          float* __restrict__ out, int nrows) {
    int t = threadIdx.x;
    int row = blockIdx.x * 64 + (t >> 2);
    if (row >= nrows) return;
    int c = (t & 3) * 4;
    float4 acc = make_float4(0.f, 0.f, 0.f, 0.f);
    int s0 = offs0[row], s1 = offs0[row + 1];
    for (int j = s0; j < s1; ++j) {
        int s = csr[j];
        float4 v = *reinterpret_cast<const float4*>(t0 + (size_t)s*DOUT + c);
        acc.x += v.x; acc.y += v.y; acc.z += v.z; acc.w += v.w;
    }
    float sc = 1.0f / fmaxf((float)(s1 - s0), 1.0f);
    acc.x *= sc; acc.y *= sc; acc.z *= sc; acc.w *= sc;
    float4 acc2 = make_float4(0.f, 0.f, 0.f, 0.f);
    int u0 = offs1[row], u1 = offs1[row + 1];
    for (int j = u0; j < u1; ++j) {
        int s = csr[j];
        float4 v = *reinterpret_cast<const float4*>(t1 + (size_t)s*DOUT + c);
        acc2.x += v.x; acc2.y += v.y; acc2.z += v.z; acc2.w += v.w;
    }
    float sc2 = 1.0f / fmaxf((float)(u1 - u0), 1.0f);
    float4 bi = *reinterpret_cast<const float4*>(bias + c);
    acc.x += acc2.x*sc2 + bi.x; acc.y += acc2.y*sc2 + bi.y;
    acc.z += acc2.z*sc2 + bi.z; acc.w += acc2.w*sc2 + bi.w;
    *reinterpret_cast<float4*>(out + (size_t)row*DOUT + c) = acc;
}

extern "C" void kernel_launch(void* const* d_in, const int* in_sizes, int n_in,
                              void* d_out, int out_size, void* d_ws, size_t ws_size,
                              hipStream_t stream) {
    const float* feat_a = (const float*)d_in[0];
    const float* feat_b = (const float*)d_in[1];
    const float* basis0 = (const float*)d_in[3];
    const float* coef0  = (const float*)d_in[4];
    const float* bias0  = (const float*)d_in[5];
    const float* basis1 = (const float*)d_in[6];
    const float* coef1  = (const float*)d_in[7];
    const float* bias1  = (const float*)d_in[8];
    const float* basis2 = (const float*)d_in[9];
    const float* coef2  = (const float*)d_in[10];
    const float* bias2  = (const float*)d_in[11];
    const int* s0 = (const int*)d_in[12]; const int* d0 = (const int*)d_in[13];
    const int* s1 = (const int*)d_in[14]; const int* d1 = (const int*)d_in[15];
    const int* s2 = (const int*)d_in[16]; const int* d2 = (const int*)d_in[17];
    const int* s3 = (const int*)d_in[18]; const int* d3 = (const int*)d_in[19];
    const int E0 = in_sizes[12], E1 = in_sizes[14], E2 = in_sizes[16], E3 = in_sizes[18];
    const int Etot = E0 + E1 + E2 + E3;

    // ---- workspace carve-up ----
    char* base = (char*)d_ws;
    auto alloc = [&](size_t bytes) { char* p = base; base += (bytes + 255) & ~(size_t)255; return p; };
    unsigned short* WT00 = (unsigned short*)alloc(HDIM*HDIM*2);
    unsigned short* WT01 = (unsigned short*)alloc(HDIM*HDIM*2);
    unsigned short* WT12 = (unsigned short*)alloc(HDIM*HDIM*2);
    unsigned short* WT13 = (unsigned short*)alloc(HDIM*HDIM*2);
    float* W20 = (float*)alloc(HDIM*DOUT*4);
    float* W21 = (float*)alloc(HDIM*DOUT*4);
    int* offs_all = (int*)alloc((NODE_TOT + 1) * 4);
    int* csr_all  = (int*)alloc((size_t)Etot * 4);
    int* bsum     = (int*)alloc(2048 * 4);
    int* deg      = (int*)alloc(NODE_TOT * 4);
    int* bcount   = (int*)alloc(NBUCKET * 4);
    int* bofs     = (int*)alloc((NBUCKET + 1) * 4);
    int* gcur     = (int*)alloc(NBUCKET * 4);
    uint2* pairs  = (uint2*)alloc((size_t)Etot * 8);
    unsigned int* fa_bf  = (unsigned int*)alloc((size_t)NA*HDIM*2);
    unsigned int* fb_bf  = (unsigned int*)alloc((size_t)NB*HDIM*2);
    unsigned int* aggA_bf = (unsigned int*)alloc((size_t)ND*HDIM*2);
    unsigned int* aggB_bf = (unsigned int*)alloc((size_t)ND*HDIM*2);
    unsigned short* h0_bf = (unsigned short*)alloc((size_t)ND*HDIM*2);
    unsigned int* t2_bf  = (unsigned int*)alloc((size_t)ND*HDIM*2);
    unsigned int* t3_bf  = (unsigned int*)alloc((size_t)ND*HDIM*2);
    float* t1a  = (float*)alloc((size_t)NA*DOUT*4);
    float* t1b  = (float*)alloc((size_t)NB*DOUT*4);
    float* out = (float*)d_out;

    const int* offsR[4] = {offs_all, offs_all + ND, offs_all + 2*ND, offs_all + 2*ND + NA};
    const int nbE = (Etot + EPB - 1) / EPB;

    // ---- 1. relation weights (bf16-transposed for MFMA) + feat bf16 conversion ----
    k_weights_bfT<<<(HDIM*HDIM+255)/256, 256, 0, stream>>>(basis0, coef0, WT00, WT01, 0, 1);
    k_weights_bfT<<<(HDIM*HDIM+255)/256, 256, 0, stream>>>(basis1, coef1, WT12, WT13, 2, 3);
    k_weights<<<(HDIM*DOUT+255)/256, 256, 0, stream>>>(basis2, coef2, W20, W21, 0, 1, HDIM*DOUT);
    k_cvt_bf16<<<(NA*16+255)/256, 256, 0, stream>>>(feat_a, fa_bf, NA*16);
    k_cvt_bf16<<<(NB*16+255)/256, 256, 0, stream>>>(feat_b, fb_bf, NB*16);

    // ---- 2. bucketed CSR build ----
    {
        hipMemsetAsync(bcount, 0, NBUCKET * 4, stream);
        k_bhist<<<nbE, 256, 0, stream>>>(s0,d0,s1,d1,s2,d2,s3,d3, E0,E1,E2, Etot, bcount);
        k_bscan<<<1, 1024, 0, stream>>>(bcount, bofs, gcur);
        k_bscatter<<<nbE, 256, 0, stream>>>(s0,d0,s1,d1,s2,d2,s3,d3, E0,E1,E2, Etot, gcur, pairs);
        k_bdeg<<<NBUCKET, 256, 0, stream>>>(pairs, bofs, deg);
        int nb = (NODE_TOT + 1023) / 1024;
        k_scan1<<<nb, 1024, 0, stream>>>(deg, offs_all, bsum, NODE_TOT);
        k_scan2<<<1, 1024, 0, stream>>>(bsum, nb);
        k_scan3<<<nb, 1024, 0, stream>>>(offs_all, bsum, NODE_TOT);
        k_bfill<<<NBUCKET, 256, 0, stream>>>(pairs, bofs, offs_all, csr_all);
    }

    // ---- 3. layer 0: gathers (bf16 out) + MFMA gemm2 -> h0 (bf16) ----
    k_gather128_bf<<<(ND+3)/4, 256, 0, stream>>>(fa_bf, offsR[0], csr_all, aggA_bf, ND);
    k_gather128_bf<<<(ND+3)/4, 256, 0, stream>>>(fb_bf, offsR[1], csr_all, aggB_bf, ND);
    k_mfma_gemm<<<(ND+63)/64, 256, 0, stream>>>((const unsigned short*)aggA_bf,
                                                (const unsigned short*)aggB_bf,
                                                WT00, WT01, bias0, 1, h0_bf, ND);

    // ---- 4. layer 1 transform (50k rows, bf16 out) via MFMA ----
    k_mfma_gemm<<<(ND+63)/64, 256, 0, stream>>>(h0_bf, nullptr, WT12, nullptr, nullptr, 0,
                                                (unsigned short*)t2_bf, ND);
    k_mfma_gemm<<<(ND+63)/64, 256, 0, stream>>>(h0_bf, nullptr, WT13, nullptr, nullptr, 0,
                                                (unsigned short*)t3_bf, ND);

    // ---- 5. fused layer-1 aggregate + bias/relu + layer-2 transform -> t1a/t1b ----
    k_gather_trans16<<<(NA+15)/16, 256, 0, stream>>>(t2_bf, offsR[2], csr_all, bias1, W20, t1a, NA);
    k_gather_trans16<<<(NB+15)/16, 256, 0, stream>>>(t3_bf, offsR[3], csr_all, bias1, W21, t1b, NB);

    // ---- 6. final combine ----
    k_gather16_combine<<<(ND+63)/64, 256, 0, stream>>>(t1a, t1b, offsR[0], offsR[1], csr_all,
                                                       bias2, out, ND);
}

// Round 10
// 339.902 us; speedup vs baseline: 1.1630x; 1.1630x over previous
//
#include <hip/hip_runtime.h>

#define NA 100000
#define NB 100000
#define ND 50000
#define HDIM 128
#define DOUT 16
// concatenated dst-node space: rel0 d:[0,ND) rel1 d:[ND,2ND) rel2 a:[2ND,2ND+NA) rel3 b:[2ND+NA,...)
#define NODE_TOT (2*ND + NA + NB)
#define BSH 9
#define BKN 512
#define NBUCKET ((NODE_TOT + BKN - 1) >> BSH)   // 586
#define EPB 4096                                 // edges per block, bucket passes

typedef __attribute__((ext_vector_type(8))) short short8v;   // 8 bf16 (4 VGPRs)
typedef __attribute__((ext_vector_type(4))) float f32x4;

__device__ __forceinline__ unsigned short f2bf(float f) {
    unsigned u = __float_as_uint(f);
    return (unsigned short)((u + 0x7fffu + ((u >> 16) & 1u)) >> 16);
}
__device__ __forceinline__ void addbf2(float& x, float& y, unsigned u) {
    x += __uint_as_float(u << 16);
    y += __uint_as_float(u & 0xffff0000u);
}

struct EdgeT { int node; int src; };
__device__ __forceinline__ EdgeT edge_at(int g,
    const int* __restrict__ s0, const int* __restrict__ d0,
    const int* __restrict__ s1, const int* __restrict__ d1,
    const int* __restrict__ s2, const int* __restrict__ d2,
    const int* __restrict__ s3, const int* __restrict__ d3,
    int E0, int E1, int E2) {
    EdgeT e;
    if (g < E0)             { e.node = d0[g];                    e.src = s0[g]; }
    else if (g < E0+E1)     { e.node = ND + d1[g-E0];            e.src = s1[g-E0]; }
    else if (g < E0+E1+E2)  { e.node = 2*ND + d2[g-E0-E1];       e.src = s2[g-E0-E1]; }
    else                    { e.node = 2*ND+NA + d3[g-E0-E1-E2]; e.src = s3[g-E0-E1-E2]; }
    return e;
}

// ---------------- weights (f32, for the 128->16 path) ----------------
__global__ __launch_bounds__(256) void k_weights(const float* __restrict__ basis,
                                                 const float* __restrict__ coef,
                                                 float* __restrict__ W0, float* __restrict__ W1,
                                                 int r0, int r1, int n) {
    int i = blockIdx.x * 256 + threadIdx.x;
    if (i >= n) return;
    float b0 = basis[i], b1 = basis[n + i];
    W0[i] = coef[r0*2+0]*b0 + coef[r0*2+1]*b1;
    W1[i] = coef[r1*2+0]*b0 + coef[r1*2+1]*b1;
}

// bf16 TRANSPOSED weights for MFMA B-operand: WT[n][k] = W[k][n], 128x128
__global__ __launch_bounds__(256) void k_weights_bfT(const float* __restrict__ basis,
                                                     const float* __restrict__ coef,
                                                     unsigned short* __restrict__ WT0,
                                                     unsigned short* __restrict__ WT1,
                                                     int r0, int r1) {
    int i = blockIdx.x * 256 + threadIdx.x;   // i = k*128 + j
    if (i >= HDIM*HDIM) return;
    int k = i >> 7, j = i & 127;
    float b0 = basis[i], b1 = basis[HDIM*HDIM + i];
    WT0[(size_t)j*HDIM + k] = f2bf(coef[r0*2+0]*b0 + coef[r0*2+1]*b1);
    WT1[(size_t)j*HDIM + k] = f2bf(coef[r1*2+0]*b0 + coef[r1*2+1]*b1);
}

// ---------------- fp32 -> bf16 conversion (8 elems/thread) ----------------
__global__ __launch_bounds__(256) void k_cvt_bf16(const float* __restrict__ in,
                                                  unsigned int* __restrict__ out, int n8) {
    int i = blockIdx.x * 256 + threadIdx.x;
    if (i >= n8) return;
    const float4 a = *(const float4*)(in + (size_t)i*8);
    const float4 b = *(const float4*)(in + (size_t)i*8 + 4);
    uint4 p;
    p.x = (unsigned)f2bf(a.x) | ((unsigned)f2bf(a.y) << 16);
    p.y = (unsigned)f2bf(a.z) | ((unsigned)f2bf(a.w) << 16);
    p.z = (unsigned)f2bf(b.x) | ((unsigned)f2bf(b.y) << 16);
    p.w = (unsigned)f2bf(b.z) | ((unsigned)f2bf(b.w) << 16);
    *(uint4*)(out + (size_t)i*4) = p;
}

// ---------------- bucketed CSR build (pairs packed: node_low9<<17 | src17) ----------------
__global__ __launch_bounds__(256) void k_bhist(const int* __restrict__ s0, const int* __restrict__ d0,
                                               const int* __restrict__ s1, const int* __restrict__ d1,
                                               const int* __restrict__ s2, const int* __restrict__ d2,
                                               const int* __restrict__ s3, const int* __restrict__ d3,
                                               int E0, int E1, int E2, int Etot,
                                               int* __restrict__ bcount) {
    __shared__ int h[NBUCKET];
    for (int i = threadIdx.x; i < NBUCKET; i += 256) h[i] = 0;
    __syncthreads();
    int g0 = blockIdx.x * EPB + threadIdx.x;
    #pragma unroll
    for (int i = 0; i < EPB/256; ++i) {
        int g = g0 + i*256;
        if (g < Etot) {
            EdgeT e = edge_at(g, s0,d0,s1,d1,s2,d2,s3,d3, E0,E1,E2);
            atomicAdd(&h[e.node >> BSH], 1);
        }
    }
    __syncthreads();
    for (int i = threadIdx.x; i < NBUCKET; i += 256)
        if (h[i]) atomicAdd(&bcount[i], h[i]);
}

__global__ __launch_bounds__(1024) void k_bscan(const int* __restrict__ bcount,
                                                int* __restrict__ bofs,
                                                int* __restrict__ gcur) {
    __shared__ int sh[1024];
    int t = threadIdx.x;
    sh[t] = (t < NBUCKET) ? bcount[t] : 0;
    __syncthreads();
    for (int off = 1; off < 1024; off <<= 1) {
        int v = (t >= off) ? sh[t - off] : 0;
        __syncthreads();
        sh[t] += v;
        __syncthreads();
    }
    if (t < NBUCKET) {
        bofs[t + 1] = sh[t];
        gcur[t] = sh[t] - bcount[t];
        if (t == 0) bofs[0] = 0;
    }
}

__global__ __launch_bounds__(256) void k_bscatter(const int* __restrict__ s0, const int* __restrict__ d0,
                                                  const int* __restrict__ s1, const int* __restrict__ d1,
                                                  const int* __restrict__ s2, const int* __restrict__ d2,
                                                  const int* __restrict__ s3, const int* __restrict__ d3,
                                                  int E0, int E1, int E2, int Etot,
                                                  int* __restrict__ gcur,
                                                  unsigned int* __restrict__ pairs) {
    __shared__ int hist[NBUCKET];
    __shared__ int base[NBUCKET];
    for (int i = threadIdx.x; i < NBUCKET; i += 256) hist[i] = 0;
    __syncthreads();
    int g0 = blockIdx.x * EPB + threadIdx.x;
    int nd[EPB/256], sr[EPB/256], rk[EPB/256];
    #pragma unroll
    for (int i = 0; i < EPB/256; ++i) {
        int g = g0 + i*256;
        if (g < Etot) {
            EdgeT e = edge_at(g, s0,d0,s1,d1,s2,d2,s3,d3, E0,E1,E2);
            nd[i] = e.node; sr[i] = e.src;
            rk[i] = atomicAdd(&hist[e.node >> BSH], 1);
        } else nd[i] = -1;
    }
    __syncthreads();
    for (int i = threadIdx.x; i < NBUCKET; i += 256)
        if (hist[i]) base[i] = atomicAdd(&gcur[i], hist[i]);
    __syncthreads();
    #pragma unroll
    for (int i = 0; i < EPB/256; ++i) {
        if (nd[i] >= 0) {
            unsigned p = ((unsigned)(nd[i] & (BKN-1)) << 17) | (unsigned)sr[i];
            pairs[base[nd[i] >> BSH] + rk[i]] = p;
        }
    }
}

__global__ __launch_bounds__(256) void k_bdeg(const unsigned int* __restrict__ pairs,
                                              const int* __restrict__ bofs,
                                              int* __restrict__ deg) {
    __shared__ int ld[BKN];
    int b = blockIdx.x;
    for (int i = threadIdx.x; i < BKN; i += 256) ld[i] = 0;
    __syncthreads();
    int j0 = bofs[b], j1 = bofs[b + 1];
    for (int j = j0 + threadIdx.x; j < j1; j += 256)
        atomicAdd(&ld[pairs[j] >> 17], 1);
    __syncthreads();
    int nbase = b << BSH;
    for (int i = threadIdx.x; i < BKN && nbase + i < NODE_TOT; i += 256)
        deg[nbase + i] = ld[i];
}

__global__ __launch_bounds__(256) void k_bfill(const unsigned int* __restrict__ pairs,
                                               const int* __restrict__ bofs,
                                               const int* __restrict__ offs,
                                               int* __restrict__ csr) {
    __shared__ int cur[BKN];
    int b = blockIdx.x;
    int nbase = b << BSH;
    for (int i = threadIdx.x; i < BKN && nbase + i < NODE_TOT; i += 256)
        cur[i] = offs[nbase + i];
    __syncthreads();
    int j0 = bofs[b], j1 = bofs[b + 1];
    for (int j = j0 + threadIdx.x; j < j1; j += 256) {
        unsigned e = pairs[j];
        int p = atomicAdd(&cur[e >> 17], 1);
        csr[p] = (int)(e & 0x1FFFFu);
    }
}

// ---------------- global scans over NODE_TOT (deg -> offs) ----------------
__global__ __launch_bounds__(1024) void k_scan1(const int* __restrict__ deg,
                                                int* __restrict__ offs,
                                                int* __restrict__ bsum, int N) {
    __shared__ int sh[1024];
    int i = blockIdx.x * 1024 + threadIdx.x;
    int v = (i < N) ? deg[i] : 0;
    sh[threadIdx.x] = v;
    __syncthreads();
    for (int off = 1; off < 1024; off <<= 1) {
        int t = (threadIdx.x >= off) ? sh[threadIdx.x - off] : 0;
        __syncthreads();
        sh[threadIdx.x] += t;
        __syncthreads();
    }
    if (i < N) offs[i + 1] = sh[threadIdx.x];
    if (threadIdx.x == 1023) bsum[blockIdx.x] = sh[1023];
    if (i == 0) offs[0] = 0;
}

__global__ __launch_bounds__(1024) void k_scan2(int* __restrict__ bsum, int nb) {
    __shared__ int sh[1024];
    int t = threadIdx.x;
    sh[t] = (t < nb) ? bsum[t] : 0;
    __syncthreads();
    for (int off = 1; off < 1024; off <<= 1) {
        int v = (t >= off) ? sh[t - off] : 0;
        __syncthreads();
        sh[t] += v;
        __syncthreads();
    }
    if (t < nb) bsum[t] = sh[t];
}

__global__ __launch_bounds__(1024) void k_scan3(int* __restrict__ offs,
                                                const int* __restrict__ bsum, int N) {
    int i = blockIdx.x * 1024 + threadIdx.x;
    if (blockIdx.x > 0 && i < N) offs[i + 1] += bsum[blockIdx.x - 1];
}

// ---------------- merged layer-0 gather: rows [0,2ND), 4 rows/wave, 16 lanes/row ----------------
// lane: sub = which row (l>>4), q = channel quad (l&15) -> 8 channels, uint4 loads.
__global__ __launch_bounds__(256) void k_gather128_ab(const unsigned int* __restrict__ ta,
                                                      const unsigned int* __restrict__ tb,
                                                      const int* __restrict__ offs,
                                                      const int* __restrict__ csr,
                                                      unsigned int* __restrict__ outbf) {
    const int t = threadIdx.x;
    const int w = t >> 6, l = t & 63;
    const int sub = l >> 4, q = l & 15;
    const int row = blockIdx.x * 16 + w * 4 + sub;     // grid exact: row < 2*ND
    const unsigned int* tbl = (row < ND) ? ta : tb;
    const int s0 = offs[row], s1 = offs[row + 1];
    float a0=0,a1=0,a2=0,a3=0,a4=0,a5=0,a6=0,a7=0;
    for (int j = 0;; j += 2) {
        bool e0 = s0 + j < s1;
        bool e1 = s0 + j + 1 < s1;
        if (!__ballot(e0)) break;
        if (e0) {
            uint4 v = *(const uint4*)(tbl + (size_t)csr[s0 + j]*64 + q*4);
            addbf2(a0,a1,v.x); addbf2(a2,a3,v.y); addbf2(a4,a5,v.z); addbf2(a6,a7,v.w);
        }
        if (e1) {
            uint4 v = *(const uint4*)(tbl + (size_t)csr[s0 + j + 1]*64 + q*4);
            addbf2(a0,a1,v.x); addbf2(a2,a3,v.y); addbf2(a4,a5,v.z); addbf2(a6,a7,v.w);
        }
    }
    float sc = 1.0f / fmaxf((float)(s1 - s0), 1.0f);
    uint4 o;
    o.x = (unsigned)f2bf(a0*sc) | ((unsigned)f2bf(a1*sc) << 16);
    o.y = (unsigned)f2bf(a2*sc) | ((unsigned)f2bf(a3*sc) << 16);
    o.z = (unsigned)f2bf(a4*sc) | ((unsigned)f2bf(a5*sc) << 16);
    o.w = (unsigned)f2bf(a6*sc) | ((unsigned)f2bf(a7*sc) << 16);
    *(uint4*)(outbf + (size_t)row*64 + q*4) = o;
}

// ---------------- MFMA GEMM (layer 0, two inputs K=256): h0 = relu(A0@W0 + A1@W1 + bias) ----------------
__global__ __launch_bounds__(256) void k_mfma_gemm2(const unsigned short* __restrict__ A0,
                                                    const unsigned short* __restrict__ A1,
                                                    const unsigned short* __restrict__ WT0,
                                                    const unsigned short* __restrict__ WT1,
                                                    const float* __restrict__ bias,
                                                    unsigned short* __restrict__ outbf, int nrows) {
    const int l = threadIdx.x & 63;
    const int w = threadIdx.x >> 6;
    const int row0 = blockIdx.x * 64;
    const int colw = w * 32;
    const int kl = (l >> 4) * 8;
    const int rl = l & 15;
    f32x4 acc[4][2];
    #pragma unroll
    for (int r = 0; r < 4; ++r) { acc[r][0] = (f32x4)0.f; acc[r][1] = (f32x4)0.f; }
    const short8v az = {0,0,0,0,0,0,0,0};
    #pragma unroll
    for (int h = 0; h < 2; ++h) {
        const unsigned short* A  = h ? A1 : A0;
        const unsigned short* WT = h ? WT1 : WT0;
        #pragma unroll
        for (int s = 0; s < 4; ++s) {
            const int k0 = s * 32;
            short8v b0 = *(const short8v*)(WT + (size_t)(colw + rl)*HDIM + k0 + kl);
            short8v b1 = *(const short8v*)(WT + (size_t)(colw + 16 + rl)*HDIM + k0 + kl);
            short8v a[4];
            #pragma unroll
            for (int r = 0; r < 4; ++r) {
                int row = row0 + r*16 + rl;
                a[r] = (row < nrows) ? *(const short8v*)(A + (size_t)row*HDIM + k0 + kl) : az;
            }
            #pragma unroll
            for (int r = 0; r < 4; ++r) {
                acc[r][0] = __builtin_amdgcn_mfma_f32_16x16x32_bf16(a[r], b0, acc[r][0], 0, 0, 0);
                acc[r][1] = __builtin_amdgcn_mfma_f32_16x16x32_bf16(a[r], b1, acc[r][1], 0, 0, 0);
            }
        }
    }
    const float bc0 = bias[colw + rl];
    const float bc1 = bias[colw + 16 + rl];
    #pragma unroll
    for (int r = 0; r < 4; ++r)
        #pragma unroll
        for (int j = 0; j < 4; ++j) {
            int row = row0 + r*16 + (l >> 4)*4 + j;
            if (row < nrows) {
                outbf[(size_t)row*HDIM + colw + rl]      = f2bf(fmaxf(acc[r][0][j] + bc0, 0.f));
                outbf[(size_t)row*HDIM + colw + 16 + rl] = f2bf(fmaxf(acc[r][1][j] + bc1, 0.f));
            }
        }
}

// ---------------- MFMA GEMM (layer 1, dual output via grid.y): t = h0 @ WT ----------------
__global__ __launch_bounds__(256) void k_mfma_dual(const unsigned short* __restrict__ A,
                                                   const unsigned short* __restrict__ WTa,
                                                   const unsigned short* __restrict__ WTb,
                                                   unsigned short* __restrict__ outa,
                                                   unsigned short* __restrict__ outb, int nrows) {
    const unsigned short* WT = blockIdx.y ? WTb : WTa;
    unsigned short* outp = blockIdx.y ? outb : outa;
    const int l = threadIdx.x & 63;
    const int w = threadIdx.x >> 6;
    const int row0 = blockIdx.x * 64;
    const int colw = w * 32;
    const int kl = (l >> 4) * 8;
    const int rl = l & 15;
    f32x4 acc[4][2];
    #pragma unroll
    for (int r = 0; r < 4; ++r) { acc[r][0] = (f32x4)0.f; acc[r][1] = (f32x4)0.f; }
    const short8v az = {0,0,0,0,0,0,0,0};
    #pragma unroll
    for (int s = 0; s < 4; ++s) {
        const int k0 = s * 32;
        short8v b0 = *(const short8v*)(WT + (size_t)(colw + rl)*HDIM + k0 + kl);
        short8v b1 = *(const short8v*)(WT + (size_t)(colw + 16 + rl)*HDIM + k0 + kl);
        short8v a[4];
        #pragma unroll
        for (int r = 0; r < 4; ++r) {
            int row = row0 + r*16 + rl;
            a[r] = (row < nrows) ? *(const short8v*)(A + (size_t)row*HDIM + k0 + kl) : az;
        }
        #pragma unroll
        for (int r = 0; r < 4; ++r) {
            acc[r][0] = __builtin_amdgcn_mfma_f32_16x16x32_bf16(a[r], b0, acc[r][0], 0, 0, 0);
            acc[r][1] = __builtin_amdgcn_mfma_f32_16x16x32_bf16(a[r], b1, acc[r][1], 0, 0, 0);
        }
    }
    #pragma unroll
    for (int r = 0; r < 4; ++r)
        #pragma unroll
        for (int j = 0; j < 4; ++j) {
            int row = row0 + r*16 + (l >> 4)*4 + j;
            if (row < nrows) {
                outp[(size_t)row*HDIM + colw + rl]      = f2bf(acc[r][0][j]);
                outp[(size_t)row*HDIM + colw + 16 + rl] = f2bf(acc[r][1][j]);
            }
        }
}

// ---------------- merged fused gather + bias/relu + 128->16 transform (a and b) ----------------
// rows are global nodes [2ND, NODE_TOT); 16 rows/block; gather: 4 rows/wave, 16 lanes/row.
__global__ __launch_bounds__(256) void k_gather_trans16_ab(const unsigned int* __restrict__ t2,
                                                           const unsigned int* __restrict__ t3,
                                                           const int* __restrict__ offs,   // offs_all (global)
                                                           const int* __restrict__ csr,
                                                           const float* __restrict__ bias,
                                                           const float* __restrict__ W20,
                                                           const float* __restrict__ W21,
                                                           float* __restrict__ t1a,
                                                           float* __restrict__ t1b) {
    __shared__ float Wl0[HDIM * DOUT];    // 8KB
    __shared__ float Wl1[HDIM * DOUT];    // 8KB
    __shared__ float vbuf[16 * 132];      // 8.25KB
    const int t = threadIdx.x;
    *(float4*)(Wl0 + t*8)     = *(const float4*)(W20 + t*8);
    *(float4*)(Wl0 + t*8 + 4) = *(const float4*)(W20 + t*8 + 4);
    *(float4*)(Wl1 + t*8)     = *(const float4*)(W21 + t*8);
    *(float4*)(Wl1 + t*8 + 4) = *(const float4*)(W21 + t*8 + 4);
    __syncthreads();
    const int w = t >> 6, l = t & 63;
    const int sub = l >> 4, q = l & 15;
    const int lrow = w * 4 + sub;
    const int node = 2*ND + blockIdx.x * 16 + lrow;    // grid exact: < NODE_TOT
    const unsigned int* tbl = (node < 2*ND + NA) ? t2 : t3;
    const int s0 = offs[node], s1 = offs[node + 1];
    float a0=0,a1=0,a2=0,a3=0,a4=0,a5=0,a6=0,a7=0;
    for (int j = 0;; j += 2) {
        bool e0 = s0 + j < s1;
        bool e1 = s0 + j + 1 < s1;
        if (!__ballot(e0)) break;
        if (e0) {
            uint4 v = *(const uint4*)(tbl + (size_t)csr[s0 + j]*64 + q*4);
            addbf2(a0,a1,v.x); addbf2(a2,a3,v.y); addbf2(a4,a5,v.z); addbf2(a6,a7,v.w);
        }
        if (e1) {
            uint4 v = *(const uint4*)(tbl + (size_t)csr[s0 + j + 1]*64 + q*4);
            addbf2(a0,a1,v.x); addbf2(a2,a3,v.y); addbf2(a4,a5,v.z); addbf2(a6,a7,v.w);
        }
    }
    const float sc = 1.0f / fmaxf((float)(s1 - s0), 1.0f);
    const float4 bi0 = *(const float4*)(bias + q*8);
    const float4 bi1 = *(const float4*)(bias + q*8 + 4);
    float4 v0, v1;
    v0.x = fmaxf(a0*sc + bi0.x, 0.f); v0.y = fmaxf(a1*sc + bi0.y, 0.f);
    v0.z = fmaxf(a2*sc + bi0.z, 0.f); v0.w = fmaxf(a3*sc + bi0.w, 0.f);
    v1.x = fmaxf(a4*sc + bi1.x, 0.f); v1.y = fmaxf(a5*sc + bi1.y, 0.f);
    v1.z = fmaxf(a6*sc + bi1.z, 0.f); v1.w = fmaxf(a7*sc + bi1.w, 0.f);
    *(float4*)(vbuf + lrow*132 + q*8)     = v0;
    *(float4*)(vbuf + lrow*132 + q*8 + 4) = v1;
    __syncthreads();
    // transform: 256 thr = 16 rows x 16 cols
    const int rr = t >> 4, jj = t & 15;
    const int node2 = 2*ND + blockIdx.x * 16 + rr;
    const bool isA = node2 < 2*ND + NA;
    const float* Wl = isA ? Wl0 : Wl1;
    const float* vr = vbuf + rr*132;
    float acc = 0.f;
    #pragma unroll 8
    for (int c = 0; c < HDIM; ++c)
        acc += vr[c] * Wl[c*DOUT + jj];
    if (isA) t1a[(size_t)(node2 - 2*ND)*DOUT + jj] = acc;
    else     t1b[(size_t)(node2 - 2*ND - NA)*DOUT + jj] = acc;
}

// final: out[d] = mean-gather(t0 via rel0) + mean-gather(t1 via rel1) + bias
__global__ __launch_bounds__(256) void k_gather16_combine(const float* __restrict__ t0,
                                                          const float* __restrict__ t1,
                                                          const int* __restrict__ offs0,
                                                          const int* __restrict__ offs1,
                                                          const int* __restrict__ csr,
                                                          const float* __restrict__ bias,
                                                          float* __restrict__ out, int nrows) {
    int t = threadIdx.x;
    int row = blockIdx.x * 64 + (t >> 2);
    if (row >= nrows) return;
    int c = (t & 3) * 4;
    float4 acc = make_float4(0.f, 0.f, 0.f, 0.f);
    int s0 = offs0[row], s1 = offs0[row + 1];
    for (int j = s0; j < s1; ++j) {
        int s = csr[j];
        float4 v = *reinterpret_cast<const float4*>(t0 + (size_t)s*DOUT + c);
        acc.x += v.x; acc.y += v.y; acc.z += v.z; acc.w += v.w;
    }
    float sc = 1.0f / fmaxf((float)(s1 - s0), 1.0f);
    acc.x *= sc; acc.y *= sc; acc.z *= sc; acc.w *= sc;
    float4 acc2 = make_float4(0.f, 0.f, 0.f, 0.f);
    int u0 = offs1[row], u1 = offs1[row + 1];
    for (int j = u0; j < u1; ++j) {
        int s = csr[j];
        float4 v = *reinterpret_cast<const float4*>(t1 + (size_t)s*DOUT + c);
        acc2.x += v.x; acc2.y += v.y; acc2.z += v.z; acc2.w += v.w;
    }
    float sc2 = 1.0f / fmaxf((float)(u1 - u0), 1.0f);
    float4 bi = *reinterpret_cast<const float4*>(bias + c);
    acc.x += acc2.x*sc2 + bi.x; acc.y += acc2.y*sc2 + bi.y;
    acc.z += acc2.z*sc2 + bi.z; acc.w += acc2.w*sc2 + bi.w;
    *reinterpret_cast<float4*>(out + (size_t)row*DOUT + c) = acc;
}

extern "C" void kernel_launch(void* const* d_in, const int* in_sizes, int n_in,
                              void* d_out, int out_size, void* d_ws, size_t ws_size,
                              hipStream_t stream) {
    const float* feat_a = (const float*)d_in[0];
    const float* feat_b = (const float*)d_in[1];
    const float* basis0 = (const float*)d_in[3];
    const float* coef0  = (const float*)d_in[4];
    const float* bias0  = (const float*)d_in[5];
    const float* basis1 = (const float*)d_in[6];
    const float* coef1  = (const float*)d_in[7];
    const float* bias1  = (const float*)d_in[8];
    const float* basis2 = (const float*)d_in[9];
    const float* coef2  = (const float*)d_in[10];
    const float* bias2  = (const float*)d_in[11];
    const int* s0 = (const int*)d_in[12]; const int* d0 = (const int*)d_in[13];
    const int* s1 = (const int*)d_in[14]; const int* d1 = (const int*)d_in[15];
    const int* s2 = (const int*)d_in[16]; const int* d2 = (const int*)d_in[17];
    const int* s3 = (const int*)d_in[18]; const int* d3 = (const int*)d_in[19];
    const int E0 = in_sizes[12], E1 = in_sizes[14], E2 = in_sizes[16], E3 = in_sizes[18];
    const int Etot = E0 + E1 + E2 + E3;

    // ---- workspace carve-up ----
    char* base = (char*)d_ws;
    auto alloc = [&](size_t bytes) { char* p = base; base += (bytes + 255) & ~(size_t)255; return p; };
    unsigned short* WT00 = (unsigned short*)alloc(HDIM*HDIM*2);
    unsigned short* WT01 = (unsigned short*)alloc(HDIM*HDIM*2);
    unsigned short* WT12 = (unsigned short*)alloc(HDIM*HDIM*2);
    unsigned short* WT13 = (unsigned short*)alloc(HDIM*HDIM*2);
    float* W20 = (float*)alloc(HDIM*DOUT*4);
    float* W21 = (float*)alloc(HDIM*DOUT*4);
    int* offs_all = (int*)alloc((NODE_TOT + 1) * 4);
    int* csr_all  = (int*)alloc((size_t)Etot * 4);
    int* bsum     = (int*)alloc(2048 * 4);
    int* deg      = (int*)alloc(NODE_TOT * 4);
    int* bcount   = (int*)alloc(NBUCKET * 4);
    int* bofs     = (int*)alloc((NBUCKET + 1) * 4);
    int* gcur     = (int*)alloc(NBUCKET * 4);
    unsigned int* pairs = (unsigned int*)alloc((size_t)Etot * 4);
    unsigned int* fa_bf  = (unsigned int*)alloc((size_t)NA*HDIM*2);
    unsigned int* fb_bf  = (unsigned int*)alloc((size_t)NB*HDIM*2);
    unsigned int* aggAB  = (unsigned int*)alloc((size_t)2*ND*HDIM*2);  // [2ND][64]
    unsigned short* h0_bf = (unsigned short*)alloc((size_t)ND*HDIM*2);
    unsigned int* t2_bf  = (unsigned int*)alloc((size_t)ND*HDIM*2);
    unsigned int* t3_bf  = (unsigned int*)alloc((size_t)ND*HDIM*2);
    float* t1a  = (float*)alloc((size_t)NA*DOUT*4);
    float* t1b  = (float*)alloc((size_t)NB*DOUT*4);
    float* out = (float*)d_out;

    const int* offsR[2] = {offs_all, offs_all + ND};
    const int nbE = (Etot + EPB - 1) / EPB;

    // ---- 1. relation weights + feat bf16 conversion ----
    k_weights_bfT<<<(HDIM*HDIM+255)/256, 256, 0, stream>>>(basis0, coef0, WT00, WT01, 0, 1);
    k_weights_bfT<<<(HDIM*HDIM+255)/256, 256, 0, stream>>>(basis1, coef1, WT12, WT13, 2, 3);
    k_weights<<<(HDIM*DOUT+255)/256, 256, 0, stream>>>(basis2, coef2, W20, W21, 0, 1, HDIM*DOUT);
    k_cvt_bf16<<<(NA*16+255)/256, 256, 0, stream>>>(feat_a, fa_bf, NA*16);
    k_cvt_bf16<<<(NB*16+255)/256, 256, 0, stream>>>(feat_b, fb_bf, NB*16);

    // ---- 2. bucketed CSR build (packed u32 pairs) ----
    {
        hipMemsetAsync(bcount, 0, NBUCKET * 4, stream);
        k_bhist<<<nbE, 256, 0, stream>>>(s0,d0,s1,d1,s2,d2,s3,d3, E0,E1,E2, Etot, bcount);
        k_bscan<<<1, 1024, 0, stream>>>(bcount, bofs, gcur);
        k_bscatter<<<nbE, 256, 0, stream>>>(s0,d0,s1,d1,s2,d2,s3,d3, E0,E1,E2, Etot, gcur, pairs);
        k_bdeg<<<NBUCKET, 256, 0, stream>>>(pairs, bofs, deg);
        int nb = (NODE_TOT + 1023) / 1024;
        k_scan1<<<nb, 1024, 0, stream>>>(deg, offs_all, bsum, NODE_TOT);
        k_scan2<<<1, 1024, 0, stream>>>(bsum, nb);
        k_scan3<<<nb, 1024, 0, stream>>>(offs_all, bsum, NODE_TOT);
        k_bfill<<<NBUCKET, 256, 0, stream>>>(pairs, bofs, offs_all, csr_all);
    }

    // ---- 3. layer 0: merged gather (a+b) + MFMA gemm2 -> h0 (bf16) ----
    k_gather128_ab<<<(2*ND)/16, 256, 0, stream>>>(fa_bf, fb_bf, offs_all, csr_all, aggAB);
    k_mfma_gemm2<<<(ND+63)/64, 256, 0, stream>>>((const unsigned short*)aggAB,
                                                 (const unsigned short*)(aggAB + (size_t)ND*64),
                                                 WT00, WT01, bias0, h0_bf, ND);

    // ---- 4. layer 1 transform (50k rows, dual output) via MFMA ----
    k_mfma_dual<<<dim3((ND+63)/64, 2), 256, 0, stream>>>(h0_bf, WT12, WT13,
                                                         (unsigned short*)t2_bf,
                                                         (unsigned short*)t3_bf, ND);

    // ---- 5. merged fused layer-1 aggregate + bias/relu + layer-2 transform ----
    k_gather_trans16_ab<<<(NA+NB)/16, 256, 0, stream>>>(t2_bf, t3_bf, offs_all, csr_all,
                                                        bias1, W20, W21, t1a, t1b);

    // ---- 6. final combine ----
    k_gather16_combine<<<(ND+63)/64, 256, 0, stream>>>(t1a, t1b, offsR[0], offsR[1], csr_all,
                                                       bias2, out, ND);
}

// Round 11
// 300.116 us; speedup vs baseline: 1.3172x; 1.1326x over previous
//
#include <hip/hip_runtime.h>

#define NA 100000
#define NB 100000
#define ND 50000
#define HDIM 128
#define DOUT 16
// concatenated dst-node space: rel0 d:[0,ND) rel1 d:[ND,2ND) rel2 a:[2ND,2ND+NA) rel3 b:[2ND+NA,...)
#define NODE_TOT (2*ND + NA + NB)
#define BSH 9
#define BKN 512
#define NBUCKET ((NODE_TOT + BKN - 1) >> BSH)   // 586
#define BCAP 8192                                // fixed pairs capacity per bucket (avg 6144 max)
#define EPB 4096                                 // edges per block, bucket passes

typedef __attribute__((ext_vector_type(8))) short short8v;   // 8 bf16 (4 VGPRs)
typedef __attribute__((ext_vector_type(4))) float f32x4;

__device__ __forceinline__ unsigned short f2bf(float f) {
    unsigned u = __float_as_uint(f);
    return (unsigned short)((u + 0x7fffu + ((u >> 16) & 1u)) >> 16);
}
__device__ __forceinline__ void addbf2(float& x, float& y, unsigned u) {
    x += __uint_as_float(u << 16);
    y += __uint_as_float(u & 0xffff0000u);
}

struct EdgeT { int node; int src; };
__device__ __forceinline__ EdgeT edge_at(int g,
    const int* __restrict__ s0, const int* __restrict__ d0,
    const int* __restrict__ s1, const int* __restrict__ d1,
    const int* __restrict__ s2, const int* __restrict__ d2,
    const int* __restrict__ s3, const int* __restrict__ d3,
    int E0, int E1, int E2) {
    EdgeT e;
    if (g < E0)             { e.node = d0[g];                    e.src = s0[g]; }
    else if (g < E0+E1)     { e.node = ND + d1[g-E0];            e.src = s1[g-E0]; }
    else if (g < E0+E1+E2)  { e.node = 2*ND + d2[g-E0-E1];       e.src = s2[g-E0-E1]; }
    else                    { e.node = 2*ND+NA + d3[g-E0-E1-E2]; e.src = s3[g-E0-E1-E2]; }
    return e;
}

// ---------------- weights (f32, for the 128->16 path) ----------------
__global__ __launch_bounds__(256) void k_weights(const float* __restrict__ basis,
                                                 const float* __restrict__ coef,
                                                 float* __restrict__ W0, float* __restrict__ W1,
                                                 int r0, int r1, int n) {
    int i = blockIdx.x * 256 + threadIdx.x;
    if (i >= n) return;
    float b0 = basis[i], b1 = basis[n + i];
    W0[i] = coef[r0*2+0]*b0 + coef[r0*2+1]*b1;
    W1[i] = coef[r1*2+0]*b0 + coef[r1*2+1]*b1;
}

// bf16 TRANSPOSED weights for MFMA B-operand: WT[n][k] = W[k][n], 128x128
__global__ __launch_bounds__(256) void k_weights_bfT(const float* __restrict__ basis,
                                                     const float* __restrict__ coef,
                                                     unsigned short* __restrict__ WT0,
                                                     unsigned short* __restrict__ WT1,
                                                     int r0, int r1) {
    int i = blockIdx.x * 256 + threadIdx.x;   // i = k*128 + j
    if (i >= HDIM*HDIM) return;
    int k = i >> 7, j = i & 127;
    float b0 = basis[i], b1 = basis[HDIM*HDIM + i];
    WT0[(size_t)j*HDIM + k] = f2bf(coef[r0*2+0]*b0 + coef[r0*2+1]*b1);
    WT1[(size_t)j*HDIM + k] = f2bf(coef[r1*2+0]*b0 + coef[r1*2+1]*b1);
}

// ---------------- fp32 -> bf16 conversion (8 elems/thread) ----------------
__global__ __launch_bounds__(256) void k_cvt_bf16(const float* __restrict__ in,
                                                  unsigned int* __restrict__ out, int n8) {
    int i = blockIdx.x * 256 + threadIdx.x;
    if (i >= n8) return;
    const float4 a = *(const float4*)(in + (size_t)i*8);
    const float4 b = *(const float4*)(in + (size_t)i*8 + 4);
    uint4 p;
    p.x = (unsigned)f2bf(a.x) | ((unsigned)f2bf(a.y) << 16);
    p.y = (unsigned)f2bf(a.z) | ((unsigned)f2bf(a.w) << 16);
    p.z = (unsigned)f2bf(b.x) | ((unsigned)f2bf(b.y) << 16);
    p.w = (unsigned)f2bf(b.z) | ((unsigned)f2bf(b.w) << 16);
    *(uint4*)(out + (size_t)i*4) = p;
}

// ---------------- bucketed CSR build (fixed-capacity buckets; no hist prepass) ----------------
__global__ __launch_bounds__(256) void k_ginit(int* __restrict__ gcur) {
    int i = blockIdx.x * 256 + threadIdx.x;
    if (i < NBUCKET) gcur[i] = i * BCAP;
}

// block-level counting sort into pairs[] (bucket regions at b*BCAP); pairs: node_low9<<17 | src17
__global__ __launch_bounds__(256) void k_bscatter(const int* __restrict__ s0, const int* __restrict__ d0,
                                                  const int* __restrict__ s1, const int* __restrict__ d1,
                                                  const int* __restrict__ s2, const int* __restrict__ d2,
                                                  const int* __restrict__ s3, const int* __restrict__ d3,
                                                  int E0, int E1, int E2, int Etot,
                                                  int* __restrict__ gcur,
                                                  unsigned int* __restrict__ pairs) {
    __shared__ int hist[NBUCKET];
    __shared__ int base[NBUCKET];
    for (int i = threadIdx.x; i < NBUCKET; i += 256) hist[i] = 0;
    __syncthreads();
    int g0 = blockIdx.x * EPB + threadIdx.x;
    int nd[EPB/256], sr[EPB/256], rk[EPB/256];
    #pragma unroll
    for (int i = 0; i < EPB/256; ++i) {
        int g = g0 + i*256;
        if (g < Etot) {
            EdgeT e = edge_at(g, s0,d0,s1,d1,s2,d2,s3,d3, E0,E1,E2);
            nd[i] = e.node; sr[i] = e.src;
            rk[i] = atomicAdd(&hist[e.node >> BSH], 1);
        } else nd[i] = -1;
    }
    __syncthreads();
    for (int i = threadIdx.x; i < NBUCKET; i += 256)
        if (hist[i]) base[i] = atomicAdd(&gcur[i], hist[i]);
    __syncthreads();
    #pragma unroll
    for (int i = 0; i < EPB/256; ++i) {
        if (nd[i] >= 0) {
            unsigned p = ((unsigned)(nd[i] & (BKN-1)) << 17) | (unsigned)sr[i];
            pairs[base[nd[i] >> BSH] + rk[i]] = p;
        }
    }
}

__global__ __launch_bounds__(256) void k_bdeg(const unsigned int* __restrict__ pairs,
                                              const int* __restrict__ gcur,
                                              int* __restrict__ deg) {
    __shared__ int ld[BKN];
    int b = blockIdx.x;
    for (int i = threadIdx.x; i < BKN; i += 256) ld[i] = 0;
    __syncthreads();
    int j0 = b * BCAP, j1 = gcur[b];
    for (int j = j0 + threadIdx.x; j < j1; j += 256)
        atomicAdd(&ld[pairs[j] >> 17], 1);
    __syncthreads();
    int nbase = b << BSH;
    for (int i = threadIdx.x; i < BKN && nbase + i < NODE_TOT; i += 256)
        deg[nbase + i] = ld[i];
}

__global__ __launch_bounds__(256) void k_bfill(const unsigned int* __restrict__ pairs,
                                               const int* __restrict__ gcur,
                                               const int* __restrict__ offs,
                                               int* __restrict__ csr) {
    __shared__ int cur[BKN];
    int b = blockIdx.x;
    int nbase = b << BSH;
    for (int i = threadIdx.x; i < BKN && nbase + i < NODE_TOT; i += 256)
        cur[i] = offs[nbase + i];
    __syncthreads();
    int j0 = b * BCAP, j1 = gcur[b];
    for (int j = j0 + threadIdx.x; j < j1; j += 256) {
        unsigned e = pairs[j];
        int p = atomicAdd(&cur[e >> 17], 1);
        csr[p] = (int)(e & 0x1FFFFu);
    }
}

// ---------------- global scans over NODE_TOT (deg -> offs) ----------------
__global__ __launch_bounds__(1024) void k_scan1(const int* __restrict__ deg,
                                                int* __restrict__ offs,
                                                int* __restrict__ bsum, int N) {
    __shared__ int sh[1024];
    int i = blockIdx.x * 1024 + threadIdx.x;
    int v = (i < N) ? deg[i] : 0;
    sh[threadIdx.x] = v;
    __syncthreads();
    for (int off = 1; off < 1024; off <<= 1) {
        int t = (threadIdx.x >= off) ? sh[threadIdx.x - off] : 0;
        __syncthreads();
        sh[threadIdx.x] += t;
        __syncthreads();
    }
    if (i < N) offs[i + 1] = sh[threadIdx.x];
    if (threadIdx.x == 1023) bsum[blockIdx.x] = sh[1023];
    if (i == 0) offs[0] = 0;
}

__global__ __launch_bounds__(1024) void k_scan2(int* __restrict__ bsum, int nb) {
    __shared__ int sh[1024];
    int t = threadIdx.x;
    sh[t] = (t < nb) ? bsum[t] : 0;
    __syncthreads();
    for (int off = 1; off < 1024; off <<= 1) {
        int v = (t >= off) ? sh[t - off] : 0;
        __syncthreads();
        sh[t] += v;
        __syncthreads();
    }
    if (t < nb) bsum[t] = sh[t];
}

__global__ __launch_bounds__(1024) void k_scan3(int* __restrict__ offs,
                                                const int* __restrict__ bsum, int N) {
    int i = blockIdx.x * 1024 + threadIdx.x;
    if (blockIdx.x > 0 && i < N) offs[i + 1] += bsum[blockIdx.x - 1];
}

// ---------------- merged layer-0 gather: 4 rows/wave, 16 lanes/row, shfl-broadcast idx ----------------
__global__ __launch_bounds__(256) void k_gather128_ab(const unsigned int* __restrict__ ta,
                                                      const unsigned int* __restrict__ tb,
                                                      const int* __restrict__ offs,
                                                      const int* __restrict__ csr,
                                                      unsigned int* __restrict__ outbf) {
    const int t = threadIdx.x;
    const int w = t >> 6, l = t & 63;
    const int sub = l >> 4, q = l & 15;
    const int row = blockIdx.x * 16 + w * 4 + sub;     // grid exact: row < 2*ND
    const unsigned int* tbl = (row < ND) ? ta : tb;
    const int s0 = offs[row];
    const int deg = offs[row + 1] - s0;
    float a0=0,a1=0,a2=0,a3=0,a4=0,a5=0,a6=0,a7=0;
    for (int j = 0; j < deg; j += 16) {
        int cnt = deg - j; if (cnt > 16) cnt = 16;
        int myidx = (j + q < deg) ? csr[s0 + j + q] : 0;   // coalesced, 1 load/lane
        #pragma unroll
        for (int k = 0; k < 16; ++k) {
            if (k < cnt) {
                int idx = __shfl(myidx, k, 16);
                uint4 v = *(const uint4*)(tbl + (size_t)idx*64 + q*4);
                addbf2(a0,a1,v.x); addbf2(a2,a3,v.y); addbf2(a4,a5,v.z); addbf2(a6,a7,v.w);
            }
        }
    }
    float sc = 1.0f / fmaxf((float)deg, 1.0f);
    uint4 o;
    o.x = (unsigned)f2bf(a0*sc) | ((unsigned)f2bf(a1*sc) << 16);
    o.y = (unsigned)f2bf(a2*sc) | ((unsigned)f2bf(a3*sc) << 16);
    o.z = (unsigned)f2bf(a4*sc) | ((unsigned)f2bf(a5*sc) << 16);
    o.w = (unsigned)f2bf(a6*sc) | ((unsigned)f2bf(a7*sc) << 16);
    *(uint4*)(outbf + (size_t)row*64 + q*4) = o;
}

// ---------------- MFMA GEMM (layer 0, two inputs K=256): h0 = relu(A0@W0 + A1@W1 + bias) ----------------
__global__ __launch_bounds__(256) void k_mfma_gemm2(const unsigned short* __restrict__ A0,
                                                    const unsigned short* __restrict__ A1,
                                                    const unsigned short* __restrict__ WT0,
                                                    const unsigned short* __restrict__ WT1,
                                                    const float* __restrict__ bias,
                                                    unsigned short* __restrict__ outbf, int nrows) {
    const int l = threadIdx.x & 63;
    const int w = threadIdx.x >> 6;
    const int row0 = blockIdx.x * 64;
    const int colw = w * 32;
    const int kl = (l >> 4) * 8;
    const int rl = l & 15;
    f32x4 acc[4][2];
    #pragma unroll
    for (int r = 0; r < 4; ++r) { acc[r][0] = (f32x4)0.f; acc[r][1] = (f32x4)0.f; }
    const short8v az = {0,0,0,0,0,0,0,0};
    #pragma unroll
    for (int h = 0; h < 2; ++h) {
        const unsigned short* A  = h ? A1 : A0;
        const unsigned short* WT = h ? WT1 : WT0;
        #pragma unroll
        for (int s = 0; s < 4; ++s) {
            const int k0 = s * 32;
            short8v b0 = *(const short8v*)(WT + (size_t)(colw + rl)*HDIM + k0 + kl);
            short8v b1 = *(const short8v*)(WT + (size_t)(colw + 16 + rl)*HDIM + k0 + kl);
            short8v a[4];
            #pragma unroll
            for (int r = 0; r < 4; ++r) {
                int row = row0 + r*16 + rl;
                a[r] = (row < nrows) ? *(const short8v*)(A + (size_t)row*HDIM + k0 + kl) : az;
            }
            #pragma unroll
            for (int r = 0; r < 4; ++r) {
                acc[r][0] = __builtin_amdgcn_mfma_f32_16x16x32_bf16(a[r], b0, acc[r][0], 0, 0, 0);
                acc[r][1] = __builtin_amdgcn_mfma_f32_16x16x32_bf16(a[r], b1, acc[r][1], 0, 0, 0);
            }
        }
    }
    const float bc0 = bias[colw + rl];
    const float bc1 = bias[colw + 16 + rl];
    #pragma unroll
    for (int r = 0; r < 4; ++r)
        #pragma unroll
        for (int j = 0; j < 4; ++j) {
            int row = row0 + r*16 + (l >> 4)*4 + j;
            if (row < nrows) {
                outbf[(size_t)row*HDIM + colw + rl]      = f2bf(fmaxf(acc[r][0][j] + bc0, 0.f));
                outbf[(size_t)row*HDIM + colw + 16 + rl] = f2bf(fmaxf(acc[r][1][j] + bc1, 0.f));
            }
        }
}

// ---------------- MFMA GEMM (layer 1, dual output via grid.y): t = h0 @ WT ----------------
__global__ __launch_bounds__(256) void k_mfma_dual(const unsigned short* __restrict__ A,
                                                   const unsigned short* __restrict__ WTa,
                                                   const unsigned short* __restrict__ WTb,
                                                   unsigned short* __restrict__ outa,
                                                   unsigned short* __restrict__ outb, int nrows) {
    const unsigned short* WT = blockIdx.y ? WTb : WTa;
    unsigned short* outp = blockIdx.y ? outb : outa;
    const int l = threadIdx.x & 63;
    const int w = threadIdx.x >> 6;
    const int row0 = blockIdx.x * 64;
    const int colw = w * 32;
    const int kl = (l >> 4) * 8;
    const int rl = l & 15;
    f32x4 acc[4][2];
    #pragma unroll
    for (int r = 0; r < 4; ++r) { acc[r][0] = (f32x4)0.f; acc[r][1] = (f32x4)0.f; }
    const short8v az = {0,0,0,0,0,0,0,0};
    #pragma unroll
    for (int s = 0; s < 4; ++s) {
        const int k0 = s * 32;
        short8v b0 = *(const short8v*)(WT + (size_t)(colw + rl)*HDIM + k0 + kl);
        short8v b1 = *(const short8v*)(WT + (size_t)(colw + 16 + rl)*HDIM + k0 + kl);
        short8v a[4];
        #pragma unroll
        for (int r = 0; r < 4; ++r) {
            int row = row0 + r*16 + rl;
            a[r] = (row < nrows) ? *(const short8v*)(A + (size_t)row*HDIM + k0 + kl) : az;
        }
        #pragma unroll
        for (int r = 0; r < 4; ++r) {
            acc[r][0] = __builtin_amdgcn_mfma_f32_16x16x32_bf16(a[r], b0, acc[r][0], 0, 0, 0);
            acc[r][1] = __builtin_amdgcn_mfma_f32_16x16x32_bf16(a[r], b1, acc[r][1], 0, 0, 0);
        }
    }
    #pragma unroll
    for (int r = 0; r < 4; ++r)
        #pragma unroll
        for (int j = 0; j < 4; ++j) {
            int row = row0 + r*16 + (l >> 4)*4 + j;
            if (row < nrows) {
                outp[(size_t)row*HDIM + colw + rl]      = f2bf(acc[r][0][j]);
                outp[(size_t)row*HDIM + colw + 16 + rl] = f2bf(acc[r][1][j]);
            }
        }
}

// ---------------- merged fused gather + bias/relu + 128->16 transform (a and b) ----------------
__global__ __launch_bounds__(256) void k_gather_trans16_ab(const unsigned int* __restrict__ t2,
                                                           const unsigned int* __restrict__ t3,
                                                           const int* __restrict__ offs,   // offs_all
                                                           const int* __restrict__ csr,
                                                           const float* __restrict__ bias,
                                                           const float* __restrict__ W20,
                                                           const float* __restrict__ W21,
                                                           float* __restrict__ t1a,
                                                           float* __restrict__ t1b) {
    __shared__ float Wl0[HDIM * DOUT];    // 8KB
    __shared__ float Wl1[HDIM * DOUT];    // 8KB
    __shared__ float vbuf[16 * 132];      // 8.25KB
    const int t = threadIdx.x;
    *(float4*)(Wl0 + t*8)     = *(const float4*)(W20 + t*8);
    *(float4*)(Wl0 + t*8 + 4) = *(const float4*)(W20 + t*8 + 4);
    *(float4*)(Wl1 + t*8)     = *(const float4*)(W21 + t*8);
    *(float4*)(Wl1 + t*8 + 4) = *(const float4*)(W21 + t*8 + 4);
    __syncthreads();
    const int w = t >> 6, l = t & 63;
    const int sub = l >> 4, q = l & 15;
    const int lrow = w * 4 + sub;
    const int node = 2*ND + blockIdx.x * 16 + lrow;    // grid exact: < NODE_TOT
    const unsigned int* tbl = (node < 2*ND + NA) ? t2 : t3;
    const int s0 = offs[node];
    const int deg = offs[node + 1] - s0;
    float a0=0,a1=0,a2=0,a3=0,a4=0,a5=0,a6=0,a7=0;
    for (int j = 0; j < deg; j += 16) {
        int cnt = deg - j; if (cnt > 16) cnt = 16;
        int myidx = (j + q < deg) ? csr[s0 + j + q] : 0;
        #pragma unroll
        for (int k = 0; k < 16; ++k) {
            if (k < cnt) {
                int idx = __shfl(myidx, k, 16);
                uint4 v = *(const uint4*)(tbl + (size_t)idx*64 + q*4);
                addbf2(a0,a1,v.x); addbf2(a2,a3,v.y); addbf2(a4,a5,v.z); addbf2(a6,a7,v.w);
            }
        }
    }
    const float sc = 1.0f / fmaxf((float)deg, 1.0f);
    const float4 bi0 = *(const float4*)(bias + q*8);
    const float4 bi1 = *(const float4*)(bias + q*8 + 4);
    float4 v0, v1;
    v0.x = fmaxf(a0*sc + bi0.x, 0.f); v0.y = fmaxf(a1*sc + bi0.y, 0.f);
    v0.z = fmaxf(a2*sc + bi0.z, 0.f); v0.w = fmaxf(a3*sc + bi0.w, 0.f);
    v1.x = fmaxf(a4*sc + bi1.x, 0.f); v1.y = fmaxf(a5*sc + bi1.y, 0.f);
    v1.z = fmaxf(a6*sc + bi1.z, 0.f); v1.w = fmaxf(a7*sc + bi1.w, 0.f);
    *(float4*)(vbuf + lrow*132 + q*8)     = v0;
    *(float4*)(vbuf + lrow*132 + q*8 + 4) = v1;
    __syncthreads();
    // transform: 256 thr = 16 rows x 16 cols
    const int rr = t >> 4, jj = t & 15;
    const int node2 = 2*ND + blockIdx.x * 16 + rr;
    const bool isA = node2 < 2*ND + NA;
    const float* Wl = isA ? Wl0 : Wl1;
    const float* vr = vbuf + rr*132;
    float acc = 0.f;
    #pragma unroll 8
    for (int c = 0; c < HDIM; ++c)
        acc += vr[c] * Wl[c*DOUT + jj];
    if (isA) t1a[(size_t)(node2 - 2*ND)*DOUT + jj] = acc;
    else     t1b[(size_t)(node2 - 2*ND - NA)*DOUT + jj] = acc;
}

// final: out[d] = mean-gather(t0 via rel0) + mean-gather(t1 via rel1) + bias
__global__ __launch_bounds__(256) void k_gather16_combine(const float* __restrict__ t0,
                                                          const float* __restrict__ t1,
                                                          const int* __restrict__ offs0,
                                                          const int* __restrict__ offs1,
                                                          const int* __restrict__ csr,
                                                          const float* __restrict__ bias,
                                                          float* __restrict__ out, int nrows) {
    int t = threadIdx.x;
    int row = blockIdx.x * 64 + (t >> 2);
    if (row >= nrows) return;
    int c = (t & 3) * 4;
    float4 acc = make_float4(0.f, 0.f, 0.f, 0.f);
    int s0 = offs0[row], s1 = offs0[row + 1];
    for (int j = s0; j < s1; ++j) {
        int s = csr[j];
        float4 v = *reinterpret_cast<const float4*>(t0 + (size_t)s*DOUT + c);
        acc.x += v.x; acc.y += v.y; acc.z += v.z; acc.w += v.w;
    }
    float sc = 1.0f / fmaxf((float)(s1 - s0), 1.0f);
    acc.x *= sc; acc.y *= sc; acc.z *= sc; acc.w *= sc;
    float4 acc2 = make_float4(0.f, 0.f, 0.f, 0.f);
    int u0 = offs1[row], u1 = offs1[row + 1];
    for (int j = u0; j < u1; ++j) {
        int s = csr[j];
        float4 v = *reinterpret_cast<const float4*>(t1 + (size_t)s*DOUT + c);
        acc2.x += v.x; acc2.y += v.y; acc2.z += v.z; acc2.w += v.w;
    }
    float sc2 = 1.0f / fmaxf((float)(u1 - u0), 1.0f);
    float4 bi = *reinterpret_cast<const float4*>(bias + c);
    acc.x += acc2.x*sc2 + bi.x; acc.y += acc2.y*sc2 + bi.y;
    acc.z += acc2.z*sc2 + bi.z; acc.w += acc2.w*sc2 + bi.w;
    *reinterpret_cast<float4*>(out + (size_t)row*DOUT + c) = acc;
}

extern "C" void kernel_launch(void* const* d_in, const int* in_sizes, int n_in,
                              void* d_out, int out_size, void* d_ws, size_t ws_size,
                              hipStream_t stream) {
    const float* feat_a = (const float*)d_in[0];
    const float* feat_b = (const float*)d_in[1];
    const float* basis0 = (const float*)d_in[3];
    const float* coef0  = (const float*)d_in[4];
    const float* bias0  = (const float*)d_in[5];
    const float* basis1 = (const float*)d_in[6];
    const float* coef1  = (const float*)d_in[7];
    const float* bias1  = (const float*)d_in[8];
    const float* basis2 = (const float*)d_in[9];
    const float* coef2  = (const float*)d_in[10];
    const float* bias2  = (const float*)d_in[11];
    const int* s0 = (const int*)d_in[12]; const int* d0 = (const int*)d_in[13];
    const int* s1 = (const int*)d_in[14]; const int* d1 = (const int*)d_in[15];
    const int* s2 = (const int*)d_in[16]; const int* d2 = (const int*)d_in[17];
    const int* s3 = (const int*)d_in[18]; const int* d3 = (const int*)d_in[19];
    const int E0 = in_sizes[12], E1 = in_sizes[14], E2 = in_sizes[16], E3 = in_sizes[18];
    const int Etot = E0 + E1 + E2 + E3;

    // ---- workspace carve-up ----
    char* base = (char*)d_ws;
    auto alloc = [&](size_t bytes) { char* p = base; base += (bytes + 255) & ~(size_t)255; return p; };
    unsigned short* WT00 = (unsigned short*)alloc(HDIM*HDIM*2);
    unsigned short* WT01 = (unsigned short*)alloc(HDIM*HDIM*2);
    unsigned short* WT12 = (unsigned short*)alloc(HDIM*HDIM*2);
    unsigned short* WT13 = (unsigned short*)alloc(HDIM*HDIM*2);
    float* W20 = (float*)alloc(HDIM*DOUT*4);
    float* W21 = (float*)alloc(HDIM*DOUT*4);
    int* offs_all = (int*)alloc((NODE_TOT + 1) * 4);
    int* csr_all  = (int*)alloc((size_t)Etot * 4);
    int* bsum     = (int*)alloc(2048 * 4);
    int* deg      = (int*)alloc(NODE_TOT * 4);
    int* gcur     = (int*)alloc(NBUCKET * 4);
    unsigned int* pairs = (unsigned int*)alloc((size_t)NBUCKET * BCAP * 4);  // 19.2MB fixed regions
    unsigned int* fa_bf  = (unsigned int*)alloc((size_t)NA*HDIM*2);
    unsigned int* fb_bf  = (unsigned int*)alloc((size_t)NB*HDIM*2);
    unsigned int* aggAB  = (unsigned int*)alloc((size_t)2*ND*HDIM*2);  // [2ND][64]
    unsigned short* h0_bf = (unsigned short*)alloc((size_t)ND*HDIM*2);
    unsigned int* t2_bf  = (unsigned int*)alloc((size_t)ND*HDIM*2);
    unsigned int* t3_bf  = (unsigned int*)alloc((size_t)ND*HDIM*2);
    float* t1a  = (float*)alloc((size_t)NA*DOUT*4);
    float* t1b  = (float*)alloc((size_t)NB*DOUT*4);
    float* out = (float*)d_out;

    const int* offsR[2] = {offs_all, offs_all + ND};
    const int nbE = (Etot + EPB - 1) / EPB;

    // ---- 1. relation weights + feat bf16 conversion ----
    k_weights_bfT<<<(HDIM*HDIM+255)/256, 256, 0, stream>>>(basis0, coef0, WT00, WT01, 0, 1);
    k_weights_bfT<<<(HDIM*HDIM+255)/256, 256, 0, stream>>>(basis1, coef1, WT12, WT13, 2, 3);
    k_weights<<<(HDIM*DOUT+255)/256, 256, 0, stream>>>(basis2, coef2, W20, W21, 0, 1, HDIM*DOUT);
    k_cvt_bf16<<<(NA*16+255)/256, 256, 0, stream>>>(feat_a, fa_bf, NA*16);
    k_cvt_bf16<<<(NB*16+255)/256, 256, 0, stream>>>(feat_b, fb_bf, NB*16);

    // ---- 2. bucketed CSR build (fixed-capacity buckets) ----
    {
        k_ginit<<<(NBUCKET+255)/256, 256, 0, stream>>>(gcur);
        k_bscatter<<<nbE, 256, 0, stream>>>(s0,d0,s1,d1,s2,d2,s3,d3, E0,E1,E2, Etot, gcur, pairs);
        k_bdeg<<<NBUCKET, 256, 0, stream>>>(pairs, gcur, deg);
        int nb = (NODE_TOT + 1023) / 1024;
        k_scan1<<<nb, 1024, 0, stream>>>(deg, offs_all, bsum, NODE_TOT);
        k_scan2<<<1, 1024, 0, stream>>>(bsum, nb);
        k_scan3<<<nb, 1024, 0, stream>>>(offs_all, bsum, NODE_TOT);
        k_bfill<<<NBUCKET, 256, 0, stream>>>(pairs, gcur, offs_all, csr_all);
    }

    // ---- 3. layer 0: merged gather (a+b) + MFMA gemm2 -> h0 (bf16) ----
    k_gather128_ab<<<(2*ND)/16, 256, 0, stream>>>(fa_bf, fb_bf, offs_all, csr_all, aggAB);
    k_mfma_gemm2<<<(ND+63)/64, 256, 0, stream>>>((const unsigned short*)aggAB,
                                                 (const unsigned short*)(aggAB + (size_t)ND*64),
                                                 WT00, WT01, bias0, h0_bf, ND);

    // ---- 4. layer 1 transform (50k rows, dual output) via MFMA ----
    k_mfma_dual<<<dim3((ND+63)/64, 2), 256, 0, stream>>>(h0_bf, WT12, WT13,
                                                         (unsigned short*)t2_bf,
                                                         (unsigned short*)t3_bf, ND);

    // ---- 5. merged fused layer-1 aggregate + bias/relu + layer-2 transform ----
    k_gather_trans16_ab<<<(NA+NB)/16, 256, 0, stream>>>(t2_bf, t3_bf, offs_all, csr_all,
                                                        bias1, W20, W21, t1a, t1b);

    // ---- 6. final combine ----
    k_gather16_combine<<<(ND+63)/64, 256, 0, stream>>>(t1a, t1b, offsR[0], offsR[1], csr_all,
                                                       bias2, out, ND);
}

// Round 12
// 276.907 us; speedup vs baseline: 1.4276x; 1.0838x over previous
//
#include <hip/hip_runtime.h>

#define NA 100000
#define NB 100000
#define ND 50000
#define HDIM 128
#define DOUT 16
// concatenated dst-node space: rel0 d:[0,ND) rel1 d:[ND,2ND) rel2 a:[2ND,2ND+NA) rel3 b:[2ND+NA,...)
#define NODE_TOT (2*ND + NA + NB)
#define BSH 9
#define BKN 512
#define NBUCKET ((NODE_TOT + BKN - 1) >> BSH)   // 586
#define BCAP 8192                                // fixed pairs capacity per bucket
#define EPB 4096                                 // edges per block, bucket passes
#define TP 136                                   // LDS tile pitch in shorts (272B = 17*16, aligned)

typedef __attribute__((ext_vector_type(8))) short short8v;   // 8 bf16 (4 VGPRs)
typedef __attribute__((ext_vector_type(4))) float f32x4;

__device__ __forceinline__ unsigned short f2bf(float f) {
    unsigned u = __float_as_uint(f);
    return (unsigned short)((u + 0x7fffu + ((u >> 16) & 1u)) >> 16);
}
__device__ __forceinline__ void addbf2(float& x, float& y, unsigned u) {
    x += __uint_as_float(u << 16);
    y += __uint_as_float(u & 0xffff0000u);
}

struct EdgeT { int node; int src; };
__device__ __forceinline__ EdgeT edge_at(int g,
    const int* __restrict__ s0, const int* __restrict__ d0,
    const int* __restrict__ s1, const int* __restrict__ d1,
    const int* __restrict__ s2, const int* __restrict__ d2,
    const int* __restrict__ s3, const int* __restrict__ d3,
    int E0, int E1, int E2) {
    EdgeT e;
    if (g < E0)             { e.node = d0[g];                    e.src = s0[g]; }
    else if (g < E0+E1)     { e.node = ND + d1[g-E0];            e.src = s1[g-E0]; }
    else if (g < E0+E1+E2)  { e.node = 2*ND + d2[g-E0-E1];       e.src = s2[g-E0-E1]; }
    else                    { e.node = 2*ND+NA + d3[g-E0-E1-E2]; e.src = s3[g-E0-E1-E2]; }
    return e;
}

// ---------------- weights (f32, for the 128->16 path) ----------------
__global__ __launch_bounds__(256) void k_weights(const float* __restrict__ basis,
                                                 const float* __restrict__ coef,
                                                 float* __restrict__ W0, float* __restrict__ W1,
                                                 int r0, int r1, int n) {
    int i = blockIdx.x * 256 + threadIdx.x;
    if (i >= n) return;
    float b0 = basis[i], b1 = basis[n + i];
    W0[i] = coef[r0*2+0]*b0 + coef[r0*2+1]*b1;
    W1[i] = coef[r1*2+0]*b0 + coef[r1*2+1]*b1;
}

// bf16 TRANSPOSED weights for MFMA B-operand: WT[n][k] = W[k][n], 128x128
__global__ __launch_bounds__(256) void k_weights_bfT(const float* __restrict__ basis,
                                                     const float* __restrict__ coef,
                                                     unsigned short* __restrict__ WT0,
                                                     unsigned short* __restrict__ WT1,
                                                     int r0, int r1) {
    int i = blockIdx.x * 256 + threadIdx.x;   // i = k*128 + j
    if (i >= HDIM*HDIM) return;
    int k = i >> 7, j = i & 127;
    float b0 = basis[i], b1 = basis[HDIM*HDIM + i];
    WT0[(size_t)j*HDIM + k] = f2bf(coef[r0*2+0]*b0 + coef[r0*2+1]*b1);
    WT1[(size_t)j*HDIM + k] = f2bf(coef[r1*2+0]*b0 + coef[r1*2+1]*b1);
}

// ---------------- fp32 -> bf16 conversion, a and b merged ----------------
__global__ __launch_bounds__(256) void k_cvt_bf16_ab(const float* __restrict__ ina,
                                                     const float* __restrict__ inb,
                                                     unsigned int* __restrict__ outa,
                                                     unsigned int* __restrict__ outb) {
    int i = blockIdx.x * 256 + threadIdx.x;    // grid exact: (NA+NB)*16
    const float* in; unsigned int* out;
    if (i < NA*16) { in = ina; out = outa; }
    else           { in = inb; out = outb; i -= NA*16; }
    const float4 a = *(const float4*)(in + (size_t)i*8);
    const float4 b = *(const float4*)(in + (size_t)i*8 + 4);
    uint4 p;
    p.x = (unsigned)f2bf(a.x) | ((unsigned)f2bf(a.y) << 16);
    p.y = (unsigned)f2bf(a.z) | ((unsigned)f2bf(a.w) << 16);
    p.z = (unsigned)f2bf(b.x) | ((unsigned)f2bf(b.y) << 16);
    p.w = (unsigned)f2bf(b.z) | ((unsigned)f2bf(b.w) << 16);
    *(uint4*)(out + (size_t)i*4) = p;
}

// ---------------- bucketed CSR build (fixed-capacity buckets) ----------------
__global__ __launch_bounds__(256) void k_ginit(int* __restrict__ gcur) {
    int i = blockIdx.x * 256 + threadIdx.x;
    if (i < NBUCKET) gcur[i] = i * BCAP;
}

__global__ __launch_bounds__(256) void k_bscatter(const int* __restrict__ s0, const int* __restrict__ d0,
                                                  const int* __restrict__ s1, const int* __restrict__ d1,
                                                  const int* __restrict__ s2, const int* __restrict__ d2,
                                                  const int* __restrict__ s3, const int* __restrict__ d3,
                                                  int E0, int E1, int E2, int Etot,
                                                  int* __restrict__ gcur,
                                                  unsigned int* __restrict__ pairs) {
    __shared__ int hist[NBUCKET];
    __shared__ int base[NBUCKET];
    for (int i = threadIdx.x; i < NBUCKET; i += 256) hist[i] = 0;
    __syncthreads();
    int g0 = blockIdx.x * EPB + threadIdx.x;
    int nd[EPB/256], sr[EPB/256], rk[EPB/256];
    #pragma unroll
    for (int i = 0; i < EPB/256; ++i) {
        int g = g0 + i*256;
        if (g < Etot) {
            EdgeT e = edge_at(g, s0,d0,s1,d1,s2,d2,s3,d3, E0,E1,E2);
            nd[i] = e.node; sr[i] = e.src;
            rk[i] = atomicAdd(&hist[e.node >> BSH], 1);
        } else nd[i] = -1;
    }
    __syncthreads();
    for (int i = threadIdx.x; i < NBUCKET; i += 256)
        if (hist[i]) base[i] = atomicAdd(&gcur[i], hist[i]);
    __syncthreads();
    #pragma unroll
    for (int i = 0; i < EPB/256; ++i) {
        if (nd[i] >= 0) {
            unsigned p = ((unsigned)(nd[i] & (BKN-1)) << 17) | (unsigned)sr[i];
            pairs[base[nd[i] >> BSH] + rk[i]] = p;
        }
    }
}

__global__ __launch_bounds__(256) void k_bdeg(const unsigned int* __restrict__ pairs,
                                              const int* __restrict__ gcur,
                                              int* __restrict__ deg) {
    __shared__ int ld[BKN];
    int b = blockIdx.x;
    for (int i = threadIdx.x; i < BKN; i += 256) ld[i] = 0;
    __syncthreads();
    int j0 = b * BCAP, j1 = gcur[b];
    for (int j = j0 + threadIdx.x; j < j1; j += 256)
        atomicAdd(&ld[pairs[j] >> 17], 1);
    __syncthreads();
    int nbase = b << BSH;
    for (int i = threadIdx.x; i < BKN && nbase + i < NODE_TOT; i += 256)
        deg[nbase + i] = ld[i];
}

__global__ __launch_bounds__(256) void k_bfill(const unsigned int* __restrict__ pairs,
                                               const int* __restrict__ gcur,
                                               const int* __restrict__ offs,
                                               int* __restrict__ csr) {
    __shared__ int cur[BKN];
    int b = blockIdx.x;
    int nbase = b << BSH;
    for (int i = threadIdx.x; i < BKN && nbase + i < NODE_TOT; i += 256)
        cur[i] = offs[nbase + i];
    __syncthreads();
    int j0 = b * BCAP, j1 = gcur[b];
    for (int j = j0 + threadIdx.x; j < j1; j += 256) {
        unsigned e = pairs[j];
        int p = atomicAdd(&cur[e >> 17], 1);
        csr[p] = (int)(e & 0x1FFFFu);
    }
}

// ---------------- global scans over NODE_TOT (deg -> offs) ----------------
__global__ __launch_bounds__(1024) void k_scan1(const int* __restrict__ deg,
                                                int* __restrict__ offs,
                                                int* __restrict__ bsum, int N) {
    __shared__ int sh[1024];
    int i = blockIdx.x * 1024 + threadIdx.x;
    int v = (i < N) ? deg[i] : 0;
    sh[threadIdx.x] = v;
    __syncthreads();
    for (int off = 1; off < 1024; off <<= 1) {
        int t = (threadIdx.x >= off) ? sh[threadIdx.x - off] : 0;
        __syncthreads();
        sh[threadIdx.x] += t;
        __syncthreads();
    }
    if (i < N) offs[i + 1] = sh[threadIdx.x];
    if (threadIdx.x == 1023) bsum[blockIdx.x] = sh[1023];
    if (i == 0) offs[0] = 0;
}

__global__ __launch_bounds__(1024) void k_scan2(int* __restrict__ bsum, int nb) {
    __shared__ int sh[1024];
    int t = threadIdx.x;
    sh[t] = (t < nb) ? bsum[t] : 0;
    __syncthreads();
    for (int off = 1; off < 1024; off <<= 1) {
        int v = (t >= off) ? sh[t - off] : 0;
        __syncthreads();
        sh[t] += v;
        __syncthreads();
    }
    if (t < nb) bsum[t] = sh[t];
}

__global__ __launch_bounds__(1024) void k_scan3(int* __restrict__ offs,
                                                const int* __restrict__ bsum, int N) {
    int i = blockIdx.x * 1024 + threadIdx.x;
    if (blockIdx.x > 0 && i < N) offs[i + 1] += bsum[blockIdx.x - 1];
}

// ---------------- FUSED layer-0: gather a+b rows into LDS, then K=256 MFMA ----------------
// block handles 64 d-rows: tiles tA (mean fa via rel0) and tB (mean fb via rel1) in LDS,
// then h0 = relu(tA@W0 + tB@W1 + bias) via mfma, bf16 out.
__global__ __launch_bounds__(256) void k_gfused_l0(const unsigned int* __restrict__ fa,
                                                   const unsigned int* __restrict__ fb,
                                                   const int* __restrict__ offs,
                                                   const int* __restrict__ csr,
                                                   const unsigned short* __restrict__ WT0,
                                                   const unsigned short* __restrict__ WT1,
                                                   const float* __restrict__ bias,
                                                   unsigned short* __restrict__ outbf, int nrows) {
    __shared__ unsigned short tA[64 * TP];   // 17.4KB
    __shared__ unsigned short tB[64 * TP];
    const int t = threadIdx.x;
    const int row0 = blockIdx.x * 64;
    // ---- gather phase: 16 concurrent gather-rows x 8 batches (64 A-rows then 64 B-rows) ----
    {
        const int q = t & 15;          // 16B chunk within row (8 channels)
        const int gslot = t >> 4;      // 0..15
        for (int batch = 0; batch < 8; ++batch) {
            int gr = batch * 16 + gslot;             // 0..127
            int lrow = gr & 63;
            bool isB = gr >= 64;
            const unsigned int* tbl = isB ? fb : fa;
            unsigned short* tile = isB ? tB : tA;
            float a0=0,a1=0,a2=0,a3=0,a4=0,a5=0,a6=0,a7=0;
            int deg = 0;
            if (row0 + lrow < nrows) {
                int node = (isB ? ND : 0) + row0 + lrow;
                int s0 = offs[node];
                deg = offs[node + 1] - s0;
                for (int j = 0; j < deg; j += 16) {
                    int cnt = deg - j; if (cnt > 16) cnt = 16;
                    int myidx = (j + q < deg) ? csr[s0 + j + q] : 0;
                    #pragma unroll
                    for (int k = 0; k < 16; ++k) {
                        if (k < cnt) {
                            int idx = __shfl(myidx, k, 16);
                            uint4 v = *(const uint4*)(tbl + (size_t)idx*64 + q*4);
                            addbf2(a0,a1,v.x); addbf2(a2,a3,v.y); addbf2(a4,a5,v.z); addbf2(a6,a7,v.w);
                        }
                    }
                }
            }
            float sc = 1.0f / fmaxf((float)deg, 1.0f);
            uint4 o;
            o.x = (unsigned)f2bf(a0*sc) | ((unsigned)f2bf(a1*sc) << 16);
            o.y = (unsigned)f2bf(a2*sc) | ((unsigned)f2bf(a3*sc) << 16);
            o.z = (unsigned)f2bf(a4*sc) | ((unsigned)f2bf(a5*sc) << 16);
            o.w = (unsigned)f2bf(a6*sc) | ((unsigned)f2bf(a7*sc) << 16);
            *(uint4*)(tile + lrow*TP + q*8) = o;
        }
    }
    __syncthreads();
    // ---- MFMA phase ----
    const int l = t & 63;
    const int w = t >> 6;
    const int colw = w * 32;
    const int kl = (l >> 4) * 8;
    const int rl = l & 15;
    f32x4 acc[4][2];
    #pragma unroll
    for (int r = 0; r < 4; ++r) { acc[r][0] = (f32x4)0.f; acc[r][1] = (f32x4)0.f; }
    #pragma unroll
    for (int h = 0; h < 2; ++h) {
        const unsigned short* tile = h ? tB : tA;
        const unsigned short* WT = h ? WT1 : WT0;
        #pragma unroll
        for (int s = 0; s < 4; ++s) {
            const int k0 = s * 32;
            short8v b0 = *(const short8v*)(WT + (size_t)(colw + rl)*HDIM + k0 + kl);
            short8v b1 = *(const short8v*)(WT + (size_t)(colw + 16 + rl)*HDIM + k0 + kl);
            short8v a[4];
            #pragma unroll
            for (int r = 0; r < 4; ++r)
                a[r] = *(const short8v*)(tile + (r*16 + rl)*TP + k0 + kl);
            #pragma unroll
            for (int r = 0; r < 4; ++r) {
                acc[r][0] = __builtin_amdgcn_mfma_f32_16x16x32_bf16(a[r], b0, acc[r][0], 0, 0, 0);
                acc[r][1] = __builtin_amdgcn_mfma_f32_16x16x32_bf16(a[r], b1, acc[r][1], 0, 0, 0);
            }
        }
    }
    const float bc0 = bias[colw + rl];
    const float bc1 = bias[colw + 16 + rl];
    #pragma unroll
    for (int r = 0; r < 4; ++r)
        #pragma unroll
        for (int j = 0; j < 4; ++j) {
            int row = row0 + r*16 + (l >> 4)*4 + j;
            if (row < nrows) {
                outbf[(size_t)row*HDIM + colw + rl]      = f2bf(fmaxf(acc[r][0][j] + bc0, 0.f));
                outbf[(size_t)row*HDIM + colw + 16 + rl] = f2bf(fmaxf(acc[r][1][j] + bc1, 0.f));
            }
        }
}

// ---------------- MFMA GEMM (layer 1, dual output via grid.y): t = h0 @ WT ----------------
__global__ __launch_bounds__(256) void k_mfma_dual(const unsigned short* __restrict__ A,
                                                   const unsigned short* __restrict__ WTa,
                                                   const unsigned short* __restrict__ WTb,
                                                   unsigned short* __restrict__ outa,
                                                   unsigned short* __restrict__ outb, int nrows) {
    const unsigned short* WT = blockIdx.y ? WTb : WTa;
    unsigned short* outp = blockIdx.y ? outb : outa;
    const int l = threadIdx.x & 63;
    const int w = threadIdx.x >> 6;
    const int row0 = blockIdx.x * 64;
    const int colw = w * 32;
    const int kl = (l >> 4) * 8;
    const int rl = l & 15;
    f32x4 acc[4][2];
    #pragma unroll
    for (int r = 0; r < 4; ++r) { acc[r][0] = (f32x4)0.f; acc[r][1] = (f32x4)0.f; }
    const short8v az = {0,0,0,0,0,0,0,0};
    #pragma unroll
    for (int s = 0; s < 4; ++s) {
        const int k0 = s * 32;
        short8v b0 = *(const short8v*)(WT + (size_t)(colw + rl)*HDIM + k0 + kl);
        short8v b1 = *(const short8v*)(WT + (size_t)(colw + 16 + rl)*HDIM + k0 + kl);
        short8v a[4];
        #pragma unroll
        for (int r = 0; r < 4; ++r) {
            int row = row0 + r*16 + rl;
            a[r] = (row < nrows) ? *(const short8v*)(A + (size_t)row*HDIM + k0 + kl) : az;
        }
        #pragma unroll
        for (int r = 0; r < 4; ++r) {
            acc[r][0] = __builtin_amdgcn_mfma_f32_16x16x32_bf16(a[r], b0, acc[r][0], 0, 0, 0);
            acc[r][1] = __builtin_amdgcn_mfma_f32_16x16x32_bf16(a[r], b1, acc[r][1], 0, 0, 0);
        }
    }
    #pragma unroll
    for (int r = 0; r < 4; ++r)
        #pragma unroll
        for (int j = 0; j < 4; ++j) {
            int row = row0 + r*16 + (l >> 4)*4 + j;
            if (row < nrows) {
                outp[(size_t)row*HDIM + colw + rl]      = f2bf(acc[r][0][j]);
                outp[(size_t)row*HDIM + colw + 16 + rl] = f2bf(acc[r][1][j]);
            }
        }
}

// ---------------- merged fused gather + bias/relu + 128->16 transform (a and b) ----------------
// NA%16==0 so each 16-row block is purely a-side or purely b-side: stage one W, transposed.
__global__ __launch_bounds__(256) void k_gather_trans16_ab(const unsigned int* __restrict__ t2,
                                                           const unsigned int* __restrict__ t3,
                                                           const int* __restrict__ offs,   // offs_all
                                                           const int* __restrict__ csr,
                                                           const float* __restrict__ bias,
                                                           const float* __restrict__ W20,
                                                           const float* __restrict__ W21,
                                                           float* __restrict__ t1a,
                                                           float* __restrict__ t1b) {
    __shared__ float WlT[16 * 132];       // 8.45KB, WlT[j][c] = W[c][j], pitch 132 (528B, 16-aligned)
    __shared__ float vbuf[16 * 132];      // 8.45KB
    const int t = threadIdx.x;
    const bool blkA = (blockIdx.x < NA/16);
    const float* W = blkA ? W20 : W21;
    {   // stage W transposed: thread handles jj = t&15, c = (t>>4)*8 .. +7
        const int jj = t & 15, c0 = (t >> 4) * 8;
        #pragma unroll
        for (int i = 0; i < 8; ++i)
            WlT[jj*132 + c0 + i] = W[(size_t)(c0 + i)*DOUT + jj];
    }
    __syncthreads();
    const int w = t >> 6, l = t & 63;
    const int sub = l >> 4, q = l & 15;
    const int lrow = w * 4 + sub;
    const int node = 2*ND + blockIdx.x * 16 + lrow;    // grid exact: < NODE_TOT
    const unsigned int* tbl = blkA ? t2 : t3;
    const int s0 = offs[node];
    const int deg = offs[node + 1] - s0;
    float a0=0,a1=0,a2=0,a3=0,a4=0,a5=0,a6=0,a7=0;
    for (int j = 0; j < deg; j += 16) {
        int cnt = deg - j; if (cnt > 16) cnt = 16;
        int myidx = (j + q < deg) ? csr[s0 + j + q] : 0;
        #pragma unroll
        for (int k = 0; k < 16; ++k) {
            if (k < cnt) {
                int idx = __shfl(myidx, k, 16);
                uint4 v = *(const uint4*)(tbl + (size_t)idx*64 + q*4);
                addbf2(a0,a1,v.x); addbf2(a2,a3,v.y); addbf2(a4,a5,v.z); addbf2(a6,a7,v.w);
            }
        }
    }
    const float sc = 1.0f / fmaxf((float)deg, 1.0f);
    const float4 bi0 = *(const float4*)(bias + q*8);
    const float4 bi1 = *(const float4*)(bias + q*8 + 4);
    float4 v0, v1;
    v0.x = fmaxf(a0*sc + bi0.x, 0.f); v0.y = fmaxf(a1*sc + bi0.y, 0.f);
    v0.z = fmaxf(a2*sc + bi0.z, 0.f); v0.w = fmaxf(a3*sc + bi0.w, 0.f);
    v1.x = fmaxf(a4*sc + bi1.x, 0.f); v1.y = fmaxf(a5*sc + bi1.y, 0.f);
    v1.z = fmaxf(a6*sc + bi1.z, 0.f); v1.w = fmaxf(a7*sc + bi1.w, 0.f);
    *(float4*)(vbuf + lrow*132 + q*8)     = v0;
    *(float4*)(vbuf + lrow*132 + q*8 + 4) = v1;
    __syncthreads();
    // transform: 256 thr = 16 rows x 16 cols, float4 LDS reads
    const int rr = t >> 4, jj = t & 15;
    const float* vr = vbuf + rr*132;
    const float* wr = WlT + jj*132;
    float4 acc4 = make_float4(0.f, 0.f, 0.f, 0.f);
    #pragma unroll 8
    for (int c4 = 0; c4 < 32; ++c4) {
        const float4 v = *(const float4*)(vr + c4*4);
        const float4 ww = *(const float4*)(wr + c4*4);
        acc4.x += v.x*ww.x; acc4.y += v.y*ww.y; acc4.z += v.z*ww.z; acc4.w += v.w*ww.w;
    }
    float acc = (acc4.x + acc4.y) + (acc4.z + acc4.w);
    const int grow = blockIdx.x * 16 + rr;
    if (blkA) t1a[(size_t)grow*DOUT + jj] = acc;
    else      t1b[(size_t)(grow - NA)*DOUT + jj] = acc;
}

// final: out[d] = mean-gather(t0 via rel0) + mean-gather(t1 via rel1) + bias
__global__ __launch_bounds__(256) void k_gather16_combine(const float* __restrict__ t0,
                                                          const float* __restrict__ t1,
                                                          const int* __restrict__ offs0,
                                                          const int* __restrict__ offs1,
                                                          const int* __restrict__ csr,
                                                          const float* __restrict__ bias,
                                                          float* __restrict__ out, int nrows) {
    int t = threadIdx.x;
    int row = blockIdx.x * 64 + (t >> 2);
    if (row >= nrows) return;
    int q = t & 3;
    int c = q * 4;
    float4 acc = make_float4(0.f, 0.f, 0.f, 0.f);
    {
        int s0 = offs0[row], deg = offs0[row + 1] - s0;
        for (int j = 0; j < deg; j += 4) {
            int cnt = deg - j; if (cnt > 4) cnt = 4;
            int myidx = (j + q < deg) ? csr[s0 + j + q] : 0;
            #pragma unroll
            for (int k = 0; k < 4; ++k) {
                if (k < cnt) {
                    int s = __shfl(myidx, k, 4);
                    float4 v = *reinterpret_cast<const float4*>(t0 + (size_t)s*DOUT + c);
                    acc.x += v.x; acc.y += v.y; acc.z += v.z; acc.w += v.w;
                }
            }
        }
        float sc = 1.0f / fmaxf((float)deg, 1.0f);
        acc.x *= sc; acc.y *= sc; acc.z *= sc; acc.w *= sc;
    }
    float4 acc2 = make_float4(0.f, 0.f, 0.f, 0.f);
    {
        int u0 = offs1[row], deg = offs1[row + 1] - u0;
        for (int j = 0; j < deg; j += 4) {
            int cnt = deg - j; if (cnt > 4) cnt = 4;
            int myidx = (j + q < deg) ? csr[u0 + j + q] : 0;
            #pragma unroll
            for (int k = 0; k < 4; ++k) {
                if (k < cnt) {
                    int s = __shfl(myidx, k, 4);
                    float4 v = *reinterpret_cast<const float4*>(t1 + (size_t)s*DOUT + c);
                    acc2.x += v.x; acc2.y += v.y; acc2.z += v.z; acc2.w += v.w;
                }
            }
        }
        float sc2 = 1.0f / fmaxf((float)deg, 1.0f);
        acc2.x *= sc2; acc2.y *= sc2; acc2.z *= sc2; acc2.w *= sc2;
    }
    float4 bi = *reinterpret_cast<const float4*>(bias + c);
    acc.x += acc2.x + bi.x; acc.y += acc2.y + bi.y;
    acc.z += acc2.z + bi.z; acc.w += acc2.w + bi.w;
    *reinterpret_cast<float4*>(out + (size_t)row*DOUT + c) = acc;
}

extern "C" void kernel_launch(void* const* d_in, const int* in_sizes, int n_in,
                              void* d_out, int out_size, void* d_ws, size_t ws_size,
                              hipStream_t stream) {
    const float* feat_a = (const float*)d_in[0];
    const float* feat_b = (const float*)d_in[1];
    const float* basis0 = (const float*)d_in[3];
    const float* coef0  = (const float*)d_in[4];
    const float* bias0  = (const float*)d_in[5];
    const float* basis1 = (const float*)d_in[6];
    const float* coef1  = (const float*)d_in[7];
    const float* bias1  = (const float*)d_in[8];
    const float* basis2 = (const float*)d_in[9];
    const float* coef2  = (const float*)d_in[10];
    const float* bias2  = (const float*)d_in[11];
    const int* s0 = (const int*)d_in[12]; const int* d0 = (const int*)d_in[13];
    const int* s1 = (const int*)d_in[14]; const int* d1 = (const int*)d_in[15];
    const int* s2 = (const int*)d_in[16]; const int* d2 = (const int*)d_in[17];
    const int* s3 = (const int*)d_in[18]; const int* d3 = (const int*)d_in[19];
    const int E0 = in_sizes[12], E1 = in_sizes[14], E2 = in_sizes[16], E3 = in_sizes[18];
    const int Etot = E0 + E1 + E2 + E3;

    // ---- workspace carve-up ----
    char* base = (char*)d_ws;
    auto alloc = [&](size_t bytes) { char* p = base; base += (bytes + 255) & ~(size_t)255; return p; };
    unsigned short* WT00 = (unsigned short*)alloc(HDIM*HDIM*2);
    unsigned short* WT01 = (unsigned short*)alloc(HDIM*HDIM*2);
    unsigned short* WT12 = (unsigned short*)alloc(HDIM*HDIM*2);
    unsigned short* WT13 = (unsigned short*)alloc(HDIM*HDIM*2);
    float* W20 = (float*)alloc(HDIM*DOUT*4);
    float* W21 = (float*)alloc(HDIM*DOUT*4);
    int* offs_all = (int*)alloc((NODE_TOT + 1) * 4);
    int* csr_all  = (int*)alloc((size_t)Etot * 4);
    int* bsum     = (int*)alloc(2048 * 4);
    int* deg      = (int*)alloc(NODE_TOT * 4);
    int* gcur     = (int*)alloc(NBUCKET * 4);
    unsigned int* pairs = (unsigned int*)alloc((size_t)NBUCKET * BCAP * 4);  // 19.2MB fixed regions
    unsigned int* fa_bf  = (unsigned int*)alloc((size_t)NA*HDIM*2);
    unsigned int* fb_bf  = (unsigned int*)alloc((size_t)NB*HDIM*2);
    unsigned short* h0_bf = (unsigned short*)alloc((size_t)ND*HDIM*2);
    unsigned int* t2_bf  = (unsigned int*)alloc((size_t)ND*HDIM*2);
    unsigned int* t3_bf  = (unsigned int*)alloc((size_t)ND*HDIM*2);
    float* t1a  = (float*)alloc((size_t)NA*DOUT*4);
    float* t1b  = (float*)alloc((size_t)NB*DOUT*4);
    float* out = (float*)d_out;

    const int* offsR[2] = {offs_all, offs_all + ND};
    const int nbE = (Etot + EPB - 1) / EPB;

    // ---- 1. relation weights + feat bf16 conversion ----
    k_weights_bfT<<<(HDIM*HDIM+255)/256, 256, 0, stream>>>(basis0, coef0, WT00, WT01, 0, 1);
    k_weights_bfT<<<(HDIM*HDIM+255)/256, 256, 0, stream>>>(basis1, coef1, WT12, WT13, 2, 3);
    k_weights<<<(HDIM*DOUT+255)/256, 256, 0, stream>>>(basis2, coef2, W20, W21, 0, 1, HDIM*DOUT);
    k_cvt_bf16_ab<<<((NA+NB)*16)/256, 256, 0, stream>>>(feat_a, feat_b, fa_bf, fb_bf);

    // ---- 2. bucketed CSR build (fixed-capacity buckets) ----
    {
        k_ginit<<<(NBUCKET+255)/256, 256, 0, stream>>>(gcur);
        k_bscatter<<<nbE, 256, 0, stream>>>(s0,d0,s1,d1,s2,d2,s3,d3, E0,E1,E2, Etot, gcur, pairs);
        k_bdeg<<<NBUCKET, 256, 0, stream>>>(pairs, gcur, deg);
        int nb = (NODE_TOT + 1023) / 1024;
        k_scan1<<<nb, 1024, 0, stream>>>(deg, offs_all, bsum, NODE_TOT);
        k_scan2<<<1, 1024, 0, stream>>>(bsum, nb);
        k_scan3<<<nb, 1024, 0, stream>>>(offs_all, bsum, NODE_TOT);
        k_bfill<<<NBUCKET, 256, 0, stream>>>(pairs, gcur, offs_all, csr_all);
    }

    // ---- 3. layer 0 fused: gather a+b into LDS + MFMA -> h0 (bf16) ----
    k_gfused_l0<<<(ND+63)/64, 256, 0, stream>>>(fa_bf, fb_bf, offs_all, csr_all,
                                                WT00, WT01, bias0, h0_bf, ND);

    // ---- 4. layer 1 transform (50k rows, dual output) via MFMA ----
    k_mfma_dual<<<dim3((ND+63)/64, 2), 256, 0, stream>>>(h0_bf, WT12, WT13,
                                                         (unsigned short*)t2_bf,
                                                         (unsigned short*)t3_bf, ND);

    // ---- 5. merged fused layer-1 aggregate + bias/relu + layer-2 transform ----
    k_gather_trans16_ab<<<(NA+NB)/16, 256, 0, stream>>>(t2_bf, t3_bf, offs_all, csr_all,
                                                        bias1, W20, W21, t1a, t1b);

    // ---- 6. final combine ----
    k_gather16_combine<<<(ND+63)/64, 256, 0, stream>>>(t1a, t1b, offsR[0], offsR[1], csr_all,
                                                       bias2, out, ND);
}